// Round 5
// baseline (1075.884 us; speedup 1.0000x reference)
//
#include <hip/hip_runtime.h>
#include <hip/hip_bf16.h>
#include <cmath>

#define D_MODEL 768
#define D_INNER 1536
#define DT_RANK 48
#define D_STATE 16
#define D_CONV  4
#define BATCH   2
#define SEQ     2048
#define BL      (BATCH * SEQ)
#define NSTATE_TOT (BATCH * D_INNER * D_STATE)   // 49152

typedef __attribute__((ext_vector_type(8))) __bf16 bf16x8;
typedef __attribute__((ext_vector_type(8))) short short8;
typedef __attribute__((ext_vector_type(4))) float f32x4;

__device__ __forceinline__ float siluf(float x) { return x / (1.f + __expf(-x)); }
__device__ __forceinline__ float softplusf(float x) {
    return (x > 20.f) ? x : log1pf(__expf(x));
}
__device__ __forceinline__ float bf2f(short s) {
    return __uint_as_float(((unsigned)(unsigned short)s) << 16);
}

// fp32 -> (hi, lo) bf16 pair, RNE.
__device__ __forceinline__ void split2(float x, short& hi, short& lo) {
    unsigned u = __float_as_uint(x);
    unsigned r = (u + 0x7fff + ((u >> 16) & 1)) >> 16;
    hi = (short)r;
    float fh = __uint_as_float(r << 16);
    float l = x - fh;
    unsigned u2 = __float_as_uint(l);
    lo = (short)((u2 + 0x7fff + ((u2 >> 16) & 1)) >> 16);
}

// Generic fp32 -> hi/lo plane splitter (8 elems per thread).
__global__ __launch_bounds__(256) void split_f32(
    const float* __restrict__ src, short* __restrict__ h, short* __restrict__ l,
    int ngroups)
{
    int gi = blockIdx.x * 256 + threadIdx.x;
    if (gi >= ngroups) return;
    const float* p = src + (size_t)gi * 8;
    float4 a = ((const float4*)p)[0];
    float4 b = ((const float4*)p)[1];
    float xv[8] = {a.x, a.y, a.z, a.w, b.x, b.y, b.z, b.w};
    short8 vh, vl;
#pragma unroll
    for (int e = 0; e < 8; ++e) { short hh, ll; split2(xv[e], hh, ll); vh[e] = hh; vl[e] = ll; }
    *(short8*)(h + (size_t)gi * 8) = vh;
    *(short8*)(l + (size_t)gi * 8) = vl;
}

// Load one K-tile's staging groups into registers.
// F32==1: Ph is fp32 (Pl unused), split in-kernel. Else Ph/Pl are bf16 planes.
template<int R, int F32>
__device__ __forceinline__ void load_regs(
    const void* __restrict__ Ph, const void* __restrict__ Pl,
    int ld, int k0, int kend, int tid, short8* rh, short8* rl)
{
    constexpr int G = R * 4;
    int i = 0;
    for (int gi = tid; gi < G; gi += 256, ++i) {
        int row = gi >> 2, k8 = (gi & 3) << 3;
        short8 vh = {0,0,0,0,0,0,0,0}, vl = {0,0,0,0,0,0,0,0};
        if (k0 + k8 + 8 <= kend) {
            if (F32) {
                const float* p = (const float*)Ph + (size_t)row * ld + k0 + k8;
                float4 a = ((const float4*)p)[0];
                float4 b = ((const float4*)p)[1];
                float xv[8] = {a.x, a.y, a.z, a.w, b.x, b.y, b.z, b.w};
#pragma unroll
                for (int e = 0; e < 8; ++e) { short hh, ll; split2(xv[e], hh, ll); vh[e] = hh; vl[e] = ll; }
            } else {
                vh = *(const short8*)((const short*)Ph + (size_t)row * ld + k0 + k8);
                vl = *(const short8*)((const short*)Pl + (size_t)row * ld + k0 + k8);
            }
        }
        rh[i] = vh; rl[i] = vl;
    }
}

template<int R>
__device__ __forceinline__ void write_lds(
    short* sh, short* sl, int tid, const short8* rh, const short8* rl)
{
    constexpr int G = R * 4;
    int i = 0;
    for (int gi = tid; gi < G; gi += 256, ++i) {
        int row = gi >> 2, k8 = (gi & 3) << 3;
        *(short8*)(sh + row * 40 + k8) = rh[i];
        *(short8*)(sl + row * 40 + k8) = rl[i];
    }
}

// C[M,N] = A[M,K] @ Bw[N,K]^T, split-bf16 3-term MFMA, reg-prefetch pipeline.
// Supports split-K via blockIdx.z (klen = K-chunk, pstride = partial-buffer stride).
template<int BM, int BN, int WM, int WN, int EPI, int AF32, int BF32>
__global__ __launch_bounds__(256) void gemm_bf(
    const void* __restrict__ Ah, const void* __restrict__ Al,
    const void* __restrict__ Bh, const void* __restrict__ Bl,
    const float* __restrict__ bias, float* __restrict__ C,
    int M, int N, int K, int lda, int ldb, int ldc, int klen, long long pstride)
{
    constexpr int NWM = BM / WM, NWN = BN / WN;
    static_assert(NWM * NWN == 4, "4 waves");
    constexpr int FM = WM / 16, FN = WN / 16;
    constexpr int NA = (BM * 4 + 255) / 256, NB = (BN * 4 + 255) / 256;

    __shared__ short sAh[BM * 40], sAl[BM * 40];
    __shared__ short sBh[BN * 40], sBl[BN * 40];

    const int tid = threadIdx.x, lane = tid & 63, wid = tid >> 6;
    const int bm0 = blockIdx.x * BM, bn0 = blockIdx.y * BN;
    const int kbeg = blockIdx.z * klen;
    const int kend = min(K, kbeg + klen);
    float* Cp = C + (long long)blockIdx.z * pstride;
    const int wm0 = (wid / NWN) * WM, wn0 = (wid % NWN) * WN;

    const void* Aht = AF32 ? (const void*)((const float*)Ah + (size_t)bm0 * lda)
                           : (const void*)((const short*)Ah + (size_t)bm0 * lda);
    const void* Alt = AF32 ? nullptr : (const void*)((const short*)Al + (size_t)bm0 * lda);
    const void* Bht = BF32 ? (const void*)((const float*)Bh + (size_t)bn0 * ldb)
                           : (const void*)((const short*)Bh + (size_t)bn0 * ldb);
    const void* Blt = BF32 ? nullptr : (const void*)((const short*)Bl + (size_t)bn0 * ldb);

    f32x4 acc[FM][FN];
#pragma unroll
    for (int i = 0; i < FM; ++i)
#pragma unroll
        for (int j = 0; j < FN; ++j)
            acc[i][j] = (f32x4){0.f, 0.f, 0.f, 0.f};

    short8 rAh[NA], rAl[NA], rBh[NB], rBl[NB];
    load_regs<BM, AF32>(Aht, Alt, lda, kbeg, kend, tid, rAh, rAl);
    load_regs<BN, BF32>(Bht, Blt, ldb, kbeg, kend, tid, rBh, rBl);

    const int rsel = lane & 15;
    const int ksel = (lane >> 4) * 8;

    for (int k0 = kbeg; k0 < kend; k0 += 32) {
        write_lds<BM>(sAh, sAl, tid, rAh, rAl);
        write_lds<BN>(sBh, sBl, tid, rBh, rBl);
        __syncthreads();
        if (k0 + 32 < kend) {
            load_regs<BM, AF32>(Aht, Alt, lda, k0 + 32, kend, tid, rAh, rAl);
            load_regs<BN, BF32>(Bht, Blt, ldb, k0 + 32, kend, tid, rBh, rBl);
        }
        bf16x8 afh[FM], afl[FM], bfh[FN], bfl[FN];
#pragma unroll
        for (int i = 0; i < FM; ++i) {
            int off = (wm0 + i * 16 + rsel) * 40 + ksel;
            afh[i] = *(const bf16x8*)(sAh + off);
            afl[i] = *(const bf16x8*)(sAl + off);
        }
#pragma unroll
        for (int j = 0; j < FN; ++j) {
            int off = (wn0 + j * 16 + rsel) * 40 + ksel;
            bfh[j] = *(const bf16x8*)(sBh + off);
            bfl[j] = *(const bf16x8*)(sBl + off);
        }
#pragma unroll
        for (int i = 0; i < FM; ++i)
#pragma unroll
            for (int j = 0; j < FN; ++j) {
                acc[i][j] = __builtin_amdgcn_mfma_f32_16x16x32_bf16(afl[i], bfh[j], acc[i][j], 0, 0, 0);
                acc[i][j] = __builtin_amdgcn_mfma_f32_16x16x32_bf16(afh[i], bfl[j], acc[i][j], 0, 0, 0);
                acc[i][j] = __builtin_amdgcn_mfma_f32_16x16x32_bf16(afh[i], bfh[j], acc[i][j], 0, 0, 0);
            }
        __syncthreads();
    }

    const int r0 = bm0 + wm0 + (lane >> 4) * 4;
    const int c0 = bn0 + wn0 + rsel;
#pragma unroll
    for (int i = 0; i < FM; ++i)
#pragma unroll
        for (int j = 0; j < FN; ++j) {
            int c = c0 + j * 16;
            if (c >= N) continue;
#pragma unroll
            for (int q = 0; q < 4; ++q) {
                int r = r0 + i * 16 + q;
                float v = acc[i][j][q];
                if (EPI == 1) { v += bias[c]; v = softplusf(v); }
                Cp[(size_t)r * ldc + c] = v;
            }
        }
}

// Causal depthwise conv (K=4) + bias + SiLU -> bf16 hi/lo planes.
__global__ __launch_bounds__(256) void conv_silu_kernel(
    const float* __restrict__ xr, const float* __restrict__ Wc,
    const float* __restrict__ bc, short* __restrict__ xsh, short* __restrict__ xsl)
{
    int idx = blockIdx.x * 256 + threadIdx.x;
    int d   = idx % D_INNER;
    int row = idx / D_INNER;
    int l   = row % SEQ;
    float w0 = Wc[d * 4 + 0], w1 = Wc[d * 4 + 1];
    float w2 = Wc[d * 4 + 2], w3 = Wc[d * 4 + 3];
    float acc = bc[d];
    const float* base = xr + (size_t)row * (2 * D_INNER) + d;
    const ptrdiff_t st = 2 * D_INNER;
    if (l >= 3) acc = fmaf(base[-3 * st], w0, acc);
    if (l >= 2) acc = fmaf(base[-2 * st], w1, acc);
    if (l >= 1) acc = fmaf(base[-1 * st], w2, acc);
    acc = fmaf(base[0], w3, acc);
    float v = siluf(acc);
    short h, lo; split2(v, h, lo);
    xsh[idx] = h; xsl[idx] = lo;
}

// Sum the 4 split-K partials -> xdbl fp32 + hi/lo planes.
__global__ __launch_bounds__(256) void reduce4_kernel(
    const float* __restrict__ part, float* __restrict__ xdbl,
    short* __restrict__ xdh, short* __restrict__ xdl)
{
    int i = blockIdx.x * 256 + threadIdx.x;   // < BL*80
    const size_t st = (size_t)BL * 80;
    float s = part[i] + part[i + st] + part[i + 2 * st] + part[i + 3 * st];
    xdbl[i] = s;
    short h, l; split2(s, h, l);
    xdh[i] = h; xdl[i] = l;
}

// ---- Chunked parallel scan, 16 states per THREAD ----
__global__ __launch_bounds__(256) void scan_part1(
    const float* __restrict__ xr, const short* __restrict__ xsh,
    const short* __restrict__ xsl, const float* __restrict__ xdbl,
    const float* __restrict__ A_log, float* __restrict__ P, float* __restrict__ S,
    int CL)
{
    const int t = blockIdx.x * 256 + threadIdx.x;
    const int d = t % D_INNER;
    const int cb = t / D_INNER;
    const int b = cb % BATCH;
    const int c = cb / BATCH;
    const int l0 = c * CL;

    float Ac[16];
#pragma unroll
    for (int q = 0; q < 4; ++q) {
        float4 v = ((const float4*)(A_log + d * 16))[q];
        Ac[q*4+0] = -__expf(v.x); Ac[q*4+1] = -__expf(v.y);
        Ac[q*4+2] = -__expf(v.z); Ac[q*4+3] = -__expf(v.w);
    }
    float h[16];
#pragma unroll
    for (int n = 0; n < 16; ++n) h[n] = 0.f;
    float sdt = 0.f;

    const float* dptr = xr   + ((size_t)b * SEQ + l0) * (2 * D_INNER) + d;
    size_t xoff       = ((size_t)b * SEQ + l0) * D_INNER + d;
    const float* brow = xdbl + ((size_t)b * SEQ + l0) * 80 + DT_RANK;

    for (int l = 0; l < CL; ++l) {
        float dt = *dptr;
        float xt = bf2f(xsh[xoff]) + bf2f(xsl[xoff]);
        float cc = dt * xt;
        float Bv[16];
#pragma unroll
        for (int q = 0; q < 4; ++q) {
            float4 v = ((const float4*)brow)[q];
            Bv[q*4+0]=v.x; Bv[q*4+1]=v.y; Bv[q*4+2]=v.z; Bv[q*4+3]=v.w;
        }
#pragma unroll
        for (int n = 0; n < 16; ++n)
            h[n] = fmaf(__expf(Ac[n] * dt), h[n], cc * Bv[n]);
        sdt += dt;
        dptr += 2 * D_INNER; xoff += D_INNER; brow += 80;
    }
#pragma unroll
    for (int n = 0; n < 16; ++n) {
        P[(size_t)t * 16 + n] = __expf(Ac[n] * sdt);
        S[(size_t)t * 16 + n] = h[n];
    }
}

__global__ __launch_bounds__(256) void scan_combine(
    const float* __restrict__ P, const float* __restrict__ S,
    float* __restrict__ Hin, int NC)
{
    const int j = blockIdx.x * 256 + threadIdx.x;   // < NSTATE_TOT
    float h = 0.f;
    for (int c = 0; c < NC; ++c) {
        size_t idx = (size_t)c * NSTATE_TOT + j;
        Hin[idx] = h;
        h = fmaf(P[idx], h, S[idx]);
    }
}

// Re-scan from Hin; y = (h·C + xt*D) * silu(res) written as hi/lo planes (in-place over xs planes).
__global__ __launch_bounds__(256) void scan_part2(
    const float* __restrict__ xr, const float* __restrict__ xdbl,
    const float* __restrict__ A_log, const float* __restrict__ Dvec,
    const float* __restrict__ Hin, short* __restrict__ xsh, short* __restrict__ xsl,
    int CL)
{
    const int t = blockIdx.x * 256 + threadIdx.x;
    const int d = t % D_INNER;
    const int cb = t / D_INNER;
    const int b = cb % BATCH;
    const int c = cb / BATCH;
    const int l0 = c * CL;

    float Ac[16];
#pragma unroll
    for (int q = 0; q < 4; ++q) {
        float4 v = ((const float4*)(A_log + d * 16))[q];
        Ac[q*4+0] = -__expf(v.x); Ac[q*4+1] = -__expf(v.y);
        Ac[q*4+2] = -__expf(v.z); Ac[q*4+3] = -__expf(v.w);
    }
    const float Dd = Dvec[d];
    float h[16];
#pragma unroll
    for (int q = 0; q < 4; ++q) {
        float4 v = ((const float4*)(Hin + (size_t)t * 16))[q];
        h[q*4+0]=v.x; h[q*4+1]=v.y; h[q*4+2]=v.z; h[q*4+3]=v.w;
    }

    const float* dptr = xr   + ((size_t)b * SEQ + l0) * (2 * D_INNER) + d;
    const float* rptr = dptr + D_INNER;
    const float* brow = xdbl + ((size_t)b * SEQ + l0) * 80 + DT_RANK;
    size_t xoff       = ((size_t)b * SEQ + l0) * D_INNER + d;

    for (int l = 0; l < CL; ++l) {
        float dt = *dptr;
        float xt = bf2f(xsh[xoff]) + bf2f(xsl[xoff]);
        float res = *rptr;
        float cc = dt * xt;
        float Bv[16], Cv[16];
#pragma unroll
        for (int q = 0; q < 4; ++q) {
            float4 v = ((const float4*)brow)[q];
            Bv[q*4+0]=v.x; Bv[q*4+1]=v.y; Bv[q*4+2]=v.z; Bv[q*4+3]=v.w;
            float4 w = ((const float4*)brow)[q + 4];
            Cv[q*4+0]=w.x; Cv[q*4+1]=w.y; Cv[q*4+2]=w.z; Cv[q*4+3]=w.w;
        }
#pragma unroll
        for (int n = 0; n < 16; ++n)
            h[n] = fmaf(__expf(Ac[n] * dt), h[n], cc * Bv[n]);
        float y0 = 0.f, y1 = 0.f, y2 = 0.f, y3 = 0.f;
#pragma unroll
        for (int n = 0; n < 4; ++n) {
            y0 = fmaf(h[n],      Cv[n],      y0);
            y1 = fmaf(h[n + 4],  Cv[n + 4],  y1);
            y2 = fmaf(h[n + 8],  Cv[n + 8],  y2);
            y3 = fmaf(h[n + 12], Cv[n + 12], y3);
        }
        float y = ((y0 + y1) + (y2 + y3)) + xt * Dd;
        y *= siluf(res);
        short hh, ll; split2(y, hh, ll);
        xsh[xoff] = hh; xsl[xoff] = ll;
        dptr += 2 * D_INNER; rptr += 2 * D_INNER; brow += 80; xoff += D_INNER;
    }
}

extern "C" void kernel_launch(void* const* d_in, const int* in_sizes, int n_in,
                              void* d_out, int out_size, void* d_ws, size_t ws_size,
                              hipStream_t stream) {
    const float* x      = (const float*)d_in[0];
    const float* W_in   = (const float*)d_in[1];
    const float* W_conv = (const float*)d_in[2];
    const float* b_conv = (const float*)d_in[3];
    const float* W_xproj= (const float*)d_in[4];
    const float* W_dt   = (const float*)d_in[5];
    const float* b_dt   = (const float*)d_in[6];
    const float* A_log  = (const float*)d_in[7];
    const float* Dv     = (const float*)d_in[8];
    const float* W_out  = (const float*)d_in[9];
    float* out = (float*)d_out;

    // ---- workspace layout (bytes) ----
    char* base = (char*)d_ws;
    size_t off = 0;
    auto alloc = [&](size_t bytes) { char* p = base + off; off += (bytes + 255) & ~(size_t)255; return p; };

    float* xr   = (float*)alloc((size_t)BL * 3072 * 4);          // in_proj out; delta/res
    short* xsh  = (short*)alloc((size_t)BL * 1536 * 2);          // xs -> y hi plane
    short* xsl  = (short*)alloc((size_t)BL * 1536 * 2);          // xs -> y lo plane
    float* xdbl = (float*)alloc((size_t)BL * 80 * 4);            // x_proj out fp32
    short* xdh  = (short*)alloc((size_t)BL * 80 * 2);
    short* xdl  = (short*)alloc((size_t)BL * 80 * 2);
    short* wxh  = (short*)alloc((size_t)80 * 1536 * 2);
    short* wxl  = (short*)alloc((size_t)80 * 1536 * 2);
    short* wdth = (short*)alloc((size_t)1536 * 48 * 2);
    short* wdtl = (short*)alloc((size_t)1536 * 48 * 2);
    short* woh  = (short*)alloc((size_t)768 * 1536 * 2);
    short* wol  = (short*)alloc((size_t)768 * 1536 * 2);
    size_t fixed_end = off;

    // Time-disjoint shared region: {W_in planes} -> {split-K partials} -> {P/S/Hin}
    const size_t winB  = (size_t)3072 * 768 * 2 * 2;             // 9.44 MB
    const size_t partB = 4ull * BL * 80 * 4;                     // 5.24 MB
    int NC = 2;
    for (int cand = 64; cand >= 2; cand >>= 1) {
        size_t scanB = 3ull * cand * NSTATE_TOT * 4;
        size_t regB = winB > partB ? winB : partB;
        if (scanB > regB) regB = scanB;
        if (fixed_end + regB <= ws_size) { NC = cand; break; }
    }
    char* region = base + fixed_end;
    short* winh = (short*)region;
    short* winl = winh + (size_t)3072 * 768;
    float* part = (float*)region;
    float* P    = (float*)region;
    float* S    = P + (size_t)NC * NSTATE_TOT;
    float* Hin  = S + (size_t)NC * NSTATE_TOT;
    const int CL = SEQ / NC;

    dim3 blk(256);

    // 0) pre-split weights to bf16 hi/lo planes
    split_f32<<<dim3((3072 * 768 / 8 + 255) / 256), blk, 0, stream>>>(W_in, winh, winl, 3072 * 768 / 8);
    split_f32<<<dim3((80 * 1536 / 8 + 255) / 256), blk, 0, stream>>>(W_xproj, wxh, wxl, 80 * 1536 / 8);
    split_f32<<<dim3((1536 * 48 / 8 + 255) / 256), blk, 0, stream>>>(W_dt, wdth, wdtl, 1536 * 48 / 8);
    split_f32<<<dim3((768 * 1536 / 8 + 255) / 256), blk, 0, stream>>>(W_out, woh, wol, 768 * 1536 / 8);

    // 1) in_proj: xr = x @ W_in^T  (A fp32 split in-kernel, B from planes)
    gemm_bf<128, 128, 64, 64, 0, 1, 0><<<dim3(BL / 128, 3072 / 128, 1), blk, 0, stream>>>(
        x, nullptr, winh, winl, nullptr, xr,
        BL, 3072, 768, 768, 768, 3072, 768, 0);

    // 2) conv + SiLU -> xs hi/lo planes
    conv_silu_kernel<<<dim3((BL * D_INNER) / 256), blk, 0, stream>>>(xr, W_conv, b_conv, xsh, xsl);

    // 3) x_proj split-K x4 -> partials
    gemm_bf<64, 80, 16, 80, 0, 0, 0><<<dim3(BL / 64, 1, 4), blk, 0, stream>>>(
        xsh, xsl, wxh, wxl, nullptr, part,
        BL, 80, 1536, 1536, 1536, 80, 384, (long long)BL * 80);
    reduce4_kernel<<<dim3(BL * 80 / 256), blk, 0, stream>>>(part, xdbl, xdh, xdl);

    // 4) delta = softplus(xdbl[:, :48] @ W_dt^T + b_dt) -> xr cols [0,1536)
    gemm_bf<128, 64, 64, 32, 1, 0, 0><<<dim3(BL / 128, 1536 / 64, 1), blk, 0, stream>>>(
        xdh, xdl, wdth, wdtl, b_dt, xr,
        BL, 1536, 48, 80, 48, 3072, 48, 0);

    // 5) chunked scan; y (gated) written as hi/lo planes in-place over xs planes
    scan_part1<<<dim3(NC * BATCH * D_INNER / 256), blk, 0, stream>>>(
        xr, xsh, xsl, xdbl, A_log, P, S, CL);
    scan_combine<<<dim3(NSTATE_TOT / 256), blk, 0, stream>>>(P, S, Hin, NC);
    scan_part2<<<dim3(NC * BATCH * D_INNER / 256), blk, 0, stream>>>(
        xr, xdbl, A_log, Dv, Hin, xsh, xsl, CL);

    // 6) out_proj: out = y @ W_out^T
    gemm_bf<128, 64, 64, 32, 0, 0, 0><<<dim3(BL / 128, 768 / 64, 1), blk, 0, stream>>>(
        xsh, xsl, woh, wol, nullptr, out,
        BL, 768, 1536, 1536, 1536, 768, 1536, 0);
}

// Round 6
// 323.227 us; speedup vs baseline: 3.3286x; 3.3286x over previous
//
#include <hip/hip_runtime.h>
#include <hip/hip_bf16.h>
#include <cmath>

#define D_MODEL 768
#define D_INNER 1536
#define DT_RANK 48
#define D_STATE 16
#define D_CONV  4
#define BATCH   2
#define SEQ     2048
#define BL      (BATCH * SEQ)
#define NSTATE_TOT (BATCH * D_INNER * D_STATE)   // 49152

typedef __attribute__((ext_vector_type(8))) __bf16 bf16x8;
typedef __attribute__((ext_vector_type(8))) short short8;
typedef __attribute__((ext_vector_type(4))) float f32x4;

__device__ __forceinline__ float siluf(float x) { return x / (1.f + __expf(-x)); }
__device__ __forceinline__ float softplusf(float x) {
    return (x > 20.f) ? x : log1pf(__expf(x));
}
__device__ __forceinline__ float bf2f(short s) {
    return __uint_as_float(((unsigned)(unsigned short)s) << 16);
}

// fp32 -> (hi, lo) bf16 pair, RNE.
__device__ __forceinline__ void split2(float x, short& hi, short& lo) {
    unsigned u = __float_as_uint(x);
    unsigned r = (u + 0x7fff + ((u >> 16) & 1)) >> 16;
    hi = (short)r;
    float fh = __uint_as_float(r << 16);
    float l = x - fh;
    unsigned u2 = __float_as_uint(l);
    lo = (short)((u2 + 0x7fff + ((u2 >> 16) & 1)) >> 16);
}

// Generic fp32 -> hi/lo plane splitter (8 elems per thread).
__global__ __launch_bounds__(256) void split_f32(
    const float* __restrict__ src, short* __restrict__ h, short* __restrict__ l,
    int ngroups)
{
    int gi = blockIdx.x * 256 + threadIdx.x;
    if (gi >= ngroups) return;
    const float* p = src + (size_t)gi * 8;
    float4 a = ((const float4*)p)[0];
    float4 b = ((const float4*)p)[1];
    float xv[8] = {a.x, a.y, a.z, a.w, b.x, b.y, b.z, b.w};
    short8 vh, vl;
#pragma unroll
    for (int e = 0; e < 8; ++e) { short hh, ll; split2(xv[e], hh, ll); vh[e] = hh; vl[e] = ll; }
    *(short8*)(h + (size_t)gi * 8) = vh;
    *(short8*)(l + (size_t)gi * 8) = vl;
}

// Load one K-tile's staging groups into registers. STATIC indexing (rule #20).
// F32==1: Ph is fp32 (Pl unused), split in-kernel. Else Ph/Pl are bf16 planes.
template<int R, int F32, int NREG>
__device__ __forceinline__ void load_regs(
    const void* __restrict__ Ph, const void* __restrict__ Pl,
    int ld, int k0, int kend, int tid, short8* rh, short8* rl)
{
    constexpr int G = R * 4;
#pragma unroll
    for (int i = 0; i < NREG; ++i) {
        int gi = tid + i * 256;
        short8 vh = {0,0,0,0,0,0,0,0}, vl = {0,0,0,0,0,0,0,0};
        if (gi < G) {
            int row = gi >> 2, k8 = (gi & 3) << 3;
            if (k0 + k8 + 8 <= kend) {
                if (F32) {
                    const float* p = (const float*)Ph + (size_t)row * ld + k0 + k8;
                    float4 a = ((const float4*)p)[0];
                    float4 b = ((const float4*)p)[1];
                    float xv[8] = {a.x, a.y, a.z, a.w, b.x, b.y, b.z, b.w};
#pragma unroll
                    for (int e = 0; e < 8; ++e) { short hh, ll; split2(xv[e], hh, ll); vh[e] = hh; vl[e] = ll; }
                } else {
                    vh = *(const short8*)((const short*)Ph + (size_t)row * ld + k0 + k8);
                    vl = *(const short8*)((const short*)Pl + (size_t)row * ld + k0 + k8);
                }
            }
        }
        rh[i] = vh; rl[i] = vl;
    }
}

template<int R, int NREG>
__device__ __forceinline__ void write_lds(
    short* sh, short* sl, int tid, const short8* rh, const short8* rl)
{
    constexpr int G = R * 4;
#pragma unroll
    for (int i = 0; i < NREG; ++i) {
        int gi = tid + i * 256;
        if (gi < G) {
            int row = gi >> 2, k8 = (gi & 3) << 3;
            *(short8*)(sh + row * 40 + k8) = rh[i];
            *(short8*)(sl + row * 40 + k8) = rl[i];
        }
    }
}

// C[M,N] = A[M,K] @ Bw[N,K]^T, split-bf16 3-term MFMA, reg-prefetch pipeline.
// Supports split-K via blockIdx.z (klen = K-chunk, pstride = partial-buffer stride).
template<int BM, int BN, int WM, int WN, int EPI, int AF32, int BF32>
__global__ __launch_bounds__(256) void gemm_bf(
    const void* __restrict__ Ah, const void* __restrict__ Al,
    const void* __restrict__ Bh, const void* __restrict__ Bl,
    const float* __restrict__ bias, float* __restrict__ C,
    int M, int N, int K, int lda, int ldb, int ldc, int klen, long long pstride)
{
    constexpr int NWM = BM / WM, NWN = BN / WN;
    static_assert(NWM * NWN == 4, "4 waves");
    constexpr int FM = WM / 16, FN = WN / 16;
    constexpr int NA = (BM * 4 + 255) / 256, NB = (BN * 4 + 255) / 256;

    __shared__ short sAh[BM * 40], sAl[BM * 40];
    __shared__ short sBh[BN * 40], sBl[BN * 40];

    const int tid = threadIdx.x, lane = tid & 63, wid = tid >> 6;
    const int bm0 = blockIdx.x * BM, bn0 = blockIdx.y * BN;
    const int kbeg = blockIdx.z * klen;
    const int kend = min(K, kbeg + klen);
    float* Cp = C + (long long)blockIdx.z * pstride;
    const int wm0 = (wid / NWN) * WM, wn0 = (wid % NWN) * WN;

    const void* Aht = AF32 ? (const void*)((const float*)Ah + (size_t)bm0 * lda)
                           : (const void*)((const short*)Ah + (size_t)bm0 * lda);
    const void* Alt = AF32 ? nullptr : (const void*)((const short*)Al + (size_t)bm0 * lda);
    const void* Bht = BF32 ? (const void*)((const float*)Bh + (size_t)bn0 * ldb)
                           : (const void*)((const short*)Bh + (size_t)bn0 * ldb);
    const void* Blt = BF32 ? nullptr : (const void*)((const short*)Bl + (size_t)bn0 * ldb);

    f32x4 acc[FM][FN];
#pragma unroll
    for (int i = 0; i < FM; ++i)
#pragma unroll
        for (int j = 0; j < FN; ++j)
            acc[i][j] = (f32x4){0.f, 0.f, 0.f, 0.f};

    short8 rAh[NA], rAl[NA], rBh[NB], rBl[NB];
    load_regs<BM, AF32, NA>(Aht, Alt, lda, kbeg, kend, tid, rAh, rAl);
    load_regs<BN, BF32, NB>(Bht, Blt, ldb, kbeg, kend, tid, rBh, rBl);

    const int rsel = lane & 15;
    const int ksel = (lane >> 4) * 8;

    for (int k0 = kbeg; k0 < kend; k0 += 32) {
        write_lds<BM, NA>(sAh, sAl, tid, rAh, rAl);
        write_lds<BN, NB>(sBh, sBl, tid, rBh, rBl);
        __syncthreads();
        if (k0 + 32 < kend) {
            load_regs<BM, AF32, NA>(Aht, Alt, lda, k0 + 32, kend, tid, rAh, rAl);
            load_regs<BN, BF32, NB>(Bht, Blt, ldb, k0 + 32, kend, tid, rBh, rBl);
        }
        bf16x8 afh[FM], afl[FM], bfh[FN], bfl[FN];
#pragma unroll
        for (int i = 0; i < FM; ++i) {
            int off = (wm0 + i * 16 + rsel) * 40 + ksel;
            afh[i] = *(const bf16x8*)(sAh + off);
            afl[i] = *(const bf16x8*)(sAl + off);
        }
#pragma unroll
        for (int j = 0; j < FN; ++j) {
            int off = (wn0 + j * 16 + rsel) * 40 + ksel;
            bfh[j] = *(const bf16x8*)(sBh + off);
            bfl[j] = *(const bf16x8*)(sBl + off);
        }
#pragma unroll
        for (int i = 0; i < FM; ++i)
#pragma unroll
            for (int j = 0; j < FN; ++j) {
                acc[i][j] = __builtin_amdgcn_mfma_f32_16x16x32_bf16(afl[i], bfh[j], acc[i][j], 0, 0, 0);
                acc[i][j] = __builtin_amdgcn_mfma_f32_16x16x32_bf16(afh[i], bfl[j], acc[i][j], 0, 0, 0);
                acc[i][j] = __builtin_amdgcn_mfma_f32_16x16x32_bf16(afh[i], bfh[j], acc[i][j], 0, 0, 0);
            }
        __syncthreads();
    }

    const int r0 = bm0 + wm0 + (lane >> 4) * 4;
    const int c0 = bn0 + wn0 + rsel;
#pragma unroll
    for (int i = 0; i < FM; ++i)
#pragma unroll
        for (int j = 0; j < FN; ++j) {
            int c = c0 + j * 16;
            if (c >= N) continue;
#pragma unroll
            for (int q = 0; q < 4; ++q) {
                int r = r0 + i * 16 + q;
                float v = acc[i][j][q];
                if (EPI == 1) { v += bias[c]; v = softplusf(v); }
                Cp[(size_t)r * ldc + c] = v;
            }
        }
}

// Causal depthwise conv (K=4) + bias + SiLU -> bf16 hi/lo planes.
__global__ __launch_bounds__(256) void conv_silu_kernel(
    const float* __restrict__ xr, const float* __restrict__ Wc,
    const float* __restrict__ bc, short* __restrict__ xsh, short* __restrict__ xsl)
{
    int idx = blockIdx.x * 256 + threadIdx.x;
    int d   = idx % D_INNER;
    int row = idx / D_INNER;
    int l   = row % SEQ;
    float w0 = Wc[d * 4 + 0], w1 = Wc[d * 4 + 1];
    float w2 = Wc[d * 4 + 2], w3 = Wc[d * 4 + 3];
    float acc = bc[d];
    const float* base = xr + (size_t)row * (2 * D_INNER) + d;
    const ptrdiff_t st = 2 * D_INNER;
    if (l >= 3) acc = fmaf(base[-3 * st], w0, acc);
    if (l >= 2) acc = fmaf(base[-2 * st], w1, acc);
    if (l >= 1) acc = fmaf(base[-1 * st], w2, acc);
    acc = fmaf(base[0], w3, acc);
    float v = siluf(acc);
    short h, lo; split2(v, h, lo);
    xsh[idx] = h; xsl[idx] = lo;
}

// Sum the 4 split-K partials -> xdbl fp32 + hi/lo planes.
__global__ __launch_bounds__(256) void reduce4_kernel(
    const float* __restrict__ part, float* __restrict__ xdbl,
    short* __restrict__ xdh, short* __restrict__ xdl)
{
    int i = blockIdx.x * 256 + threadIdx.x;   // < BL*80
    const size_t st = (size_t)BL * 80;
    float s = part[i] + part[i + st] + part[i + 2 * st] + part[i + 3 * st];
    xdbl[i] = s;
    short h, l; split2(s, h, l);
    xdh[i] = h; xdl[i] = l;
}

// ---- Chunked parallel scan, 16 states per THREAD ----
__global__ __launch_bounds__(256) void scan_part1(
    const float* __restrict__ xr, const short* __restrict__ xsh,
    const short* __restrict__ xsl, const float* __restrict__ xdbl,
    const float* __restrict__ A_log, float* __restrict__ P, float* __restrict__ S,
    int CL)
{
    const int t = blockIdx.x * 256 + threadIdx.x;
    const int d = t % D_INNER;
    const int cb = t / D_INNER;
    const int b = cb % BATCH;
    const int c = cb / BATCH;
    const int l0 = c * CL;

    float Ac[16];
#pragma unroll
    for (int q = 0; q < 4; ++q) {
        float4 v = ((const float4*)(A_log + d * 16))[q];
        Ac[q*4+0] = -__expf(v.x); Ac[q*4+1] = -__expf(v.y);
        Ac[q*4+2] = -__expf(v.z); Ac[q*4+3] = -__expf(v.w);
    }
    float h[16];
#pragma unroll
    for (int n = 0; n < 16; ++n) h[n] = 0.f;
    float sdt = 0.f;

    const float* dptr = xr   + ((size_t)b * SEQ + l0) * (2 * D_INNER) + d;
    size_t xoff       = ((size_t)b * SEQ + l0) * D_INNER + d;
    const float* brow = xdbl + ((size_t)b * SEQ + l0) * 80 + DT_RANK;

    for (int l = 0; l < CL; ++l) {
        float dt = *dptr;
        float xt = bf2f(xsh[xoff]) + bf2f(xsl[xoff]);
        float cc = dt * xt;
        float Bv[16];
#pragma unroll
        for (int q = 0; q < 4; ++q) {
            float4 v = ((const float4*)brow)[q];
            Bv[q*4+0]=v.x; Bv[q*4+1]=v.y; Bv[q*4+2]=v.z; Bv[q*4+3]=v.w;
        }
#pragma unroll
        for (int n = 0; n < 16; ++n)
            h[n] = fmaf(__expf(Ac[n] * dt), h[n], cc * Bv[n]);
        sdt += dt;
        dptr += 2 * D_INNER; xoff += D_INNER; brow += 80;
    }
#pragma unroll
    for (int n = 0; n < 16; ++n) {
        P[(size_t)t * 16 + n] = __expf(Ac[n] * sdt);
        S[(size_t)t * 16 + n] = h[n];
    }
}

__global__ __launch_bounds__(256) void scan_combine(
    const float* __restrict__ P, const float* __restrict__ S,
    float* __restrict__ Hin, int NC)
{
    const int j = blockIdx.x * 256 + threadIdx.x;   // < NSTATE_TOT
    float h = 0.f;
    for (int c = 0; c < NC; ++c) {
        size_t idx = (size_t)c * NSTATE_TOT + j;
        Hin[idx] = h;
        h = fmaf(P[idx], h, S[idx]);
    }
}

// Re-scan from Hin; y = (h·C + xt*D) * silu(res) written as hi/lo planes (in-place over xs planes).
__global__ __launch_bounds__(256) void scan_part2(
    const float* __restrict__ xr, const float* __restrict__ xdbl,
    const float* __restrict__ A_log, const float* __restrict__ Dvec,
    const float* __restrict__ Hin, short* __restrict__ xsh, short* __restrict__ xsl,
    int CL)
{
    const int t = blockIdx.x * 256 + threadIdx.x;
    const int d = t % D_INNER;
    const int cb = t / D_INNER;
    const int b = cb % BATCH;
    const int c = cb / BATCH;
    const int l0 = c * CL;

    float Ac[16];
#pragma unroll
    for (int q = 0; q < 4; ++q) {
        float4 v = ((const float4*)(A_log + d * 16))[q];
        Ac[q*4+0] = -__expf(v.x); Ac[q*4+1] = -__expf(v.y);
        Ac[q*4+2] = -__expf(v.z); Ac[q*4+3] = -__expf(v.w);
    }
    const float Dd = Dvec[d];
    float h[16];
#pragma unroll
    for (int q = 0; q < 4; ++q) {
        float4 v = ((const float4*)(Hin + (size_t)t * 16))[q];
        h[q*4+0]=v.x; h[q*4+1]=v.y; h[q*4+2]=v.z; h[q*4+3]=v.w;
    }

    const float* dptr = xr   + ((size_t)b * SEQ + l0) * (2 * D_INNER) + d;
    const float* rptr = dptr + D_INNER;
    const float* brow = xdbl + ((size_t)b * SEQ + l0) * 80 + DT_RANK;
    size_t xoff       = ((size_t)b * SEQ + l0) * D_INNER + d;

    for (int l = 0; l < CL; ++l) {
        float dt = *dptr;
        float xt = bf2f(xsh[xoff]) + bf2f(xsl[xoff]);
        float res = *rptr;
        float cc = dt * xt;
        float Bv[16], Cv[16];
#pragma unroll
        for (int q = 0; q < 4; ++q) {
            float4 v = ((const float4*)brow)[q];
            Bv[q*4+0]=v.x; Bv[q*4+1]=v.y; Bv[q*4+2]=v.z; Bv[q*4+3]=v.w;
            float4 w = ((const float4*)brow)[q + 4];
            Cv[q*4+0]=w.x; Cv[q*4+1]=w.y; Cv[q*4+2]=w.z; Cv[q*4+3]=w.w;
        }
#pragma unroll
        for (int n = 0; n < 16; ++n)
            h[n] = fmaf(__expf(Ac[n] * dt), h[n], cc * Bv[n]);
        float y0 = 0.f, y1 = 0.f, y2 = 0.f, y3 = 0.f;
#pragma unroll
        for (int n = 0; n < 4; ++n) {
            y0 = fmaf(h[n],      Cv[n],      y0);
            y1 = fmaf(h[n + 4],  Cv[n + 4],  y1);
            y2 = fmaf(h[n + 8],  Cv[n + 8],  y2);
            y3 = fmaf(h[n + 12], Cv[n + 12], y3);
        }
        float y = ((y0 + y1) + (y2 + y3)) + xt * Dd;
        y *= siluf(res);
        short hh, ll; split2(y, hh, ll);
        xsh[xoff] = hh; xsl[xoff] = ll;
        dptr += 2 * D_INNER; rptr += 2 * D_INNER; brow += 80; xoff += D_INNER;
    }
}

extern "C" void kernel_launch(void* const* d_in, const int* in_sizes, int n_in,
                              void* d_out, int out_size, void* d_ws, size_t ws_size,
                              hipStream_t stream) {
    const float* x      = (const float*)d_in[0];
    const float* W_in   = (const float*)d_in[1];
    const float* W_conv = (const float*)d_in[2];
    const float* b_conv = (const float*)d_in[3];
    const float* W_xproj= (const float*)d_in[4];
    const float* W_dt   = (const float*)d_in[5];
    const float* b_dt   = (const float*)d_in[6];
    const float* A_log  = (const float*)d_in[7];
    const float* Dv     = (const float*)d_in[8];
    const float* W_out  = (const float*)d_in[9];
    float* out = (float*)d_out;

    // ---- workspace layout (bytes) ----
    char* base = (char*)d_ws;
    size_t off = 0;
    auto alloc = [&](size_t bytes) { char* p = base + off; off += (bytes + 255) & ~(size_t)255; return p; };

    float* xr   = (float*)alloc((size_t)BL * 3072 * 4);          // in_proj out; delta/res
    short* xsh  = (short*)alloc((size_t)BL * 1536 * 2);          // xs -> y hi plane
    short* xsl  = (short*)alloc((size_t)BL * 1536 * 2);          // xs -> y lo plane
    float* xdbl = (float*)alloc((size_t)BL * 80 * 4);            // x_proj out fp32
    short* xdh  = (short*)alloc((size_t)BL * 80 * 2);
    short* xdl  = (short*)alloc((size_t)BL * 80 * 2);
    short* wxh  = (short*)alloc((size_t)80 * 1536 * 2);
    short* wxl  = (short*)alloc((size_t)80 * 1536 * 2);
    short* wdth = (short*)alloc((size_t)1536 * 48 * 2);
    short* wdtl = (short*)alloc((size_t)1536 * 48 * 2);
    short* woh  = (short*)alloc((size_t)768 * 1536 * 2);
    short* wol  = (short*)alloc((size_t)768 * 1536 * 2);
    size_t fixed_end = off;

    // Time-disjoint shared region: {W_in planes} -> {split-K partials} -> {P/S/Hin}
    const size_t winB  = (size_t)3072 * 768 * 2 * 2;             // 9.44 MB
    const size_t partB = 4ull * BL * 80 * 4;                     // 5.24 MB
    int NC = 2;
    for (int cand = 64; cand >= 2; cand >>= 1) {
        size_t scanB = 3ull * cand * NSTATE_TOT * 4;
        size_t regB = winB > partB ? winB : partB;
        if (scanB > regB) regB = scanB;
        if (fixed_end + regB <= ws_size) { NC = cand; break; }
    }
    char* region = base + fixed_end;
    short* winh = (short*)region;
    short* winl = winh + (size_t)3072 * 768;
    float* part = (float*)region;
    float* P    = (float*)region;
    float* S    = P + (size_t)NC * NSTATE_TOT;
    float* Hin  = S + (size_t)NC * NSTATE_TOT;
    const int CL = SEQ / NC;

    dim3 blk(256);

    // 0) pre-split weights to bf16 hi/lo planes
    split_f32<<<dim3((3072 * 768 / 8 + 255) / 256), blk, 0, stream>>>(W_in, winh, winl, 3072 * 768 / 8);
    split_f32<<<dim3((80 * 1536 / 8 + 255) / 256), blk, 0, stream>>>(W_xproj, wxh, wxl, 80 * 1536 / 8);
    split_f32<<<dim3((1536 * 48 / 8 + 255) / 256), blk, 0, stream>>>(W_dt, wdth, wdtl, 1536 * 48 / 8);
    split_f32<<<dim3((768 * 1536 / 8 + 255) / 256), blk, 0, stream>>>(W_out, woh, wol, 768 * 1536 / 8);

    // 1) in_proj: xr = x @ W_in^T  (A fp32 split in-kernel, B from planes)
    gemm_bf<128, 128, 64, 64, 0, 1, 0><<<dim3(BL / 128, 3072 / 128, 1), blk, 0, stream>>>(
        x, nullptr, winh, winl, nullptr, xr,
        BL, 3072, 768, 768, 768, 3072, 768, 0);

    // 2) conv + SiLU -> xs hi/lo planes
    conv_silu_kernel<<<dim3((BL * D_INNER) / 256), blk, 0, stream>>>(xr, W_conv, b_conv, xsh, xsl);

    // 3) x_proj split-K x4 -> partials
    gemm_bf<64, 80, 16, 80, 0, 0, 0><<<dim3(BL / 64, 1, 4), blk, 0, stream>>>(
        xsh, xsl, wxh, wxl, nullptr, part,
        BL, 80, 1536, 1536, 1536, 80, 384, (long long)BL * 80);
    reduce4_kernel<<<dim3(BL * 80 / 256), blk, 0, stream>>>(part, xdbl, xdh, xdl);

    // 4) delta = softplus(xdbl[:, :48] @ W_dt^T + b_dt) -> xr cols [0,1536)
    gemm_bf<128, 64, 64, 32, 1, 0, 0><<<dim3(BL / 128, 1536 / 64, 1), blk, 0, stream>>>(
        xdh, xdl, wdth, wdtl, b_dt, xr,
        BL, 1536, 48, 80, 48, 3072, 48, 0);

    // 5) chunked scan; y (gated) written as hi/lo planes in-place over xs planes
    scan_part1<<<dim3(NC * BATCH * D_INNER / 256), blk, 0, stream>>>(
        xr, xsh, xsl, xdbl, A_log, P, S, CL);
    scan_combine<<<dim3(NSTATE_TOT / 256), blk, 0, stream>>>(P, S, Hin, NC);
    scan_part2<<<dim3(NC * BATCH * D_INNER / 256), blk, 0, stream>>>(
        xr, xdbl, A_log, Dv, Hin, xsh, xsl, CL);

    // 6) out_proj: out = y @ W_out^T
    gemm_bf<128, 64, 64, 32, 0, 0, 0><<<dim3(BL / 128, 768 / 64, 1), blk, 0, stream>>>(
        xsh, xsl, woh, wol, nullptr, out,
        BL, 768, 1536, 1536, 1536, 768, 1536, 0);
}

// Round 7
// 276.632 us; speedup vs baseline: 3.8892x; 1.1684x over previous
//
#include <hip/hip_runtime.h>
#include <hip/hip_bf16.h>
#include <cmath>

#define D_MODEL 768
#define D_INNER 1536
#define DT_RANK 48
#define D_STATE 16
#define D_CONV  4
#define BATCH   2
#define SEQ     2048
#define BL      (BATCH * SEQ)
#define NSTATE_TOT (BATCH * D_INNER * D_STATE)   // 49152

typedef __attribute__((ext_vector_type(8))) __bf16 bf16x8;
typedef __attribute__((ext_vector_type(8))) short short8;
typedef __attribute__((ext_vector_type(4))) float f32x4;

__device__ __forceinline__ float siluf(float x) { return x / (1.f + __expf(-x)); }
__device__ __forceinline__ float softplusf(float x) {
    return (x > 20.f) ? x : log1pf(__expf(x));
}
__device__ __forceinline__ float bf2f(short s) {
    return __uint_as_float(((unsigned)(unsigned short)s) << 16);
}

// fp32 -> (hi, lo) bf16 pair, RNE.
__device__ __forceinline__ void split2(float x, short& hi, short& lo) {
    unsigned u = __float_as_uint(x);
    unsigned r = (u + 0x7fff + ((u >> 16) & 1)) >> 16;
    hi = (short)r;
    float fh = __uint_as_float(r << 16);
    float l = x - fh;
    unsigned u2 = __float_as_uint(l);
    lo = (short)((u2 + 0x7fff + ((u2 >> 16) & 1)) >> 16);
}

// async global->LDS, 16 bytes per lane. LDS dest is wave-uniform base + lane*16.
__device__ __forceinline__ void gload16(const void* g, void* l) {
    __builtin_amdgcn_global_load_lds(
        (const __attribute__((address_space(1))) void*)g,
        (__attribute__((address_space(3))) void*)l, 16, 0, 0);
}

// Generic fp32 -> hi/lo plane splitter (8 elems per thread).
__global__ __launch_bounds__(256) void split_f32(
    const float* __restrict__ src, short* __restrict__ h, short* __restrict__ l,
    int ngroups)
{
    int gi = blockIdx.x * 256 + threadIdx.x;
    if (gi >= ngroups) return;
    const float* p = src + (size_t)gi * 8;
    float4 a = ((const float4*)p)[0];
    float4 b = ((const float4*)p)[1];
    float xv[8] = {a.x, a.y, a.z, a.w, b.x, b.y, b.z, b.w};
    short8 vh, vl;
#pragma unroll
    for (int e = 0; e < 8; ++e) { short hh, ll; split2(xv[e], hh, ll); vh[e] = hh; vl[e] = ll; }
    *(short8*)(h + (size_t)gi * 8) = vh;
    *(short8*)(l + (size_t)gi * 8) = vl;
}

// Split with K-padding: src [rows][K] fp32 -> planes [rows][LDK], cols>=K zeroed.
__global__ __launch_bounds__(256) void split_pad_kernel(
    const float* __restrict__ src, short* __restrict__ h, short* __restrict__ l,
    int rows, int K, int LDK)
{
    int i = blockIdx.x * 256 + threadIdx.x;
    if (i >= rows * LDK) return;
    int r = i / LDK, c = i % LDK;
    float v = (c < K) ? src[(size_t)r * K + c] : 0.f;
    short hh, ll; split2(v, hh, ll);
    h[i] = hh; l[i] = ll;
}

// Stage one bf16 plane tile [ROWS][32] into linear LDS via global_load_lds.
// Source is pre-swizzled per lane: LDS slot (r, j) holds k-group j ^ ((r>>1)&3),
// so the swizzled ds_read on the consumer side is bank-conflict-minimal.
// gp points at (tile_row0, k0); ldk in shorts.
template<int ROWS>
__device__ __forceinline__ void stage_plane(
    const short* __restrict__ gp, int ldk, short* lds, int wid, int lane)
{
    constexpr int CH = ROWS / 16;            // 1KB chunks (16 rows x 64B)
    const int rr = lane >> 2, jj = lane & 3;
    for (int c = wid; c < CH; c += 4) {
        int r = c * 16 + rr;
        int kg = jj ^ ((r >> 1) & 3);
        gload16(gp + (size_t)r * ldk + kg * 8, lds + c * 512);
    }
}

// C[M,N] = A[M,K] @ Bw[N,K]^T, split-bf16 3-term MFMA.
// A/B are pre-split bf16 hi/lo planes. K (and klen) must be multiples of 32.
// Split-K via blockIdx.z (klen = K-chunk, pstride = partial-buffer stride).
// EPI==1: C = softplus(C + bias[n]).
template<int BM, int BN, int WM, int WN, int EPI>
__global__ __launch_bounds__(256) void gemm_g(
    const short* __restrict__ Ah, const short* __restrict__ Al,
    const short* __restrict__ Bh, const short* __restrict__ Bl,
    const float* __restrict__ bias, float* __restrict__ C,
    int M, int N, int K, int lda, int ldb, int ldc, int klen, long long pstride)
{
    constexpr int NWM = BM / WM, NWN = BN / WN;
    static_assert(NWM * NWN == 4, "4 waves");
    constexpr int FM = WM / 16, FN = WN / 16;

    __shared__ short sAh[BM * 32], sAl[BM * 32];
    __shared__ short sBh[BN * 32], sBl[BN * 32];

    const int tid = threadIdx.x, lane = tid & 63, wid = tid >> 6;
    const int bm0 = blockIdx.x * BM, bn0 = blockIdx.y * BN;
    const int kbeg = blockIdx.z * klen;
    const int kend = min(K, kbeg + klen);
    float* Cp = C + (long long)blockIdx.z * pstride;
    const int wm0 = (wid / NWN) * WM, wn0 = (wid % NWN) * WN;

    const short* Aht = Ah + (size_t)bm0 * lda;
    const short* Alt = Al + (size_t)bm0 * lda;
    const short* Bht = Bh + (size_t)bn0 * ldb;
    const short* Blt = Bl + (size_t)bn0 * ldb;

    f32x4 acc[FM][FN];
#pragma unroll
    for (int i = 0; i < FM; ++i)
#pragma unroll
        for (int j = 0; j < FN; ++j)
            acc[i][j] = (f32x4){0.f, 0.f, 0.f, 0.f};

    const int rsel = lane & 15;
    const int kg = lane >> 4;       // k-group (8 bf16 each)

    for (int k0 = kbeg; k0 < kend; k0 += 32) {
        stage_plane<BM>(Aht + k0, lda, sAh, wid, lane);
        stage_plane<BM>(Alt + k0, lda, sAl, wid, lane);
        stage_plane<BN>(Bht + k0, ldb, sBh, wid, lane);
        stage_plane<BN>(Blt + k0, ldb, sBl, wid, lane);
        __syncthreads();            // drains vmcnt then barrier

        bf16x8 afh[FM], afl[FM], bfh[FN], bfl[FN];
#pragma unroll
        for (int i = 0; i < FM; ++i) {
            int row = wm0 + i * 16 + rsel;
            int off = row * 32 + ((kg ^ ((row >> 1) & 3)) << 3);
            afh[i] = *(const bf16x8*)(sAh + off);
            afl[i] = *(const bf16x8*)(sAl + off);
        }
#pragma unroll
        for (int j = 0; j < FN; ++j) {
            int row = wn0 + j * 16 + rsel;
            int off = row * 32 + ((kg ^ ((row >> 1) & 3)) << 3);
            bfh[j] = *(const bf16x8*)(sBh + off);
            bfl[j] = *(const bf16x8*)(sBl + off);
        }
#pragma unroll
        for (int i = 0; i < FM; ++i)
#pragma unroll
            for (int j = 0; j < FN; ++j) {
                acc[i][j] = __builtin_amdgcn_mfma_f32_16x16x32_bf16(afl[i], bfh[j], acc[i][j], 0, 0, 0);
                acc[i][j] = __builtin_amdgcn_mfma_f32_16x16x32_bf16(afh[i], bfl[j], acc[i][j], 0, 0, 0);
                acc[i][j] = __builtin_amdgcn_mfma_f32_16x16x32_bf16(afh[i], bfh[j], acc[i][j], 0, 0, 0);
            }
        __syncthreads();            // protect LDS from next stage
    }

    const int r0 = bm0 + wm0 + (lane >> 4) * 4;
    const int c0 = bn0 + wn0 + rsel;
#pragma unroll
    for (int i = 0; i < FM; ++i)
#pragma unroll
        for (int j = 0; j < FN; ++j) {
            int c = c0 + j * 16;
            if (c >= N) continue;
#pragma unroll
            for (int q = 0; q < 4; ++q) {
                int r = r0 + i * 16 + q;
                float v = acc[i][j][q];
                if (EPI == 1) { v += bias[c]; v = softplusf(v); }
                Cp[(size_t)r * ldc + c] = v;
            }
        }
}

// Causal depthwise conv (K=4) + bias + SiLU -> bf16 hi/lo planes.
__global__ __launch_bounds__(256) void conv_silu_kernel(
    const float* __restrict__ xr, const float* __restrict__ Wc,
    const float* __restrict__ bc, short* __restrict__ xsh, short* __restrict__ xsl)
{
    int idx = blockIdx.x * 256 + threadIdx.x;
    int d   = idx % D_INNER;
    int row = idx / D_INNER;
    int l   = row % SEQ;
    float w0 = Wc[d * 4 + 0], w1 = Wc[d * 4 + 1];
    float w2 = Wc[d * 4 + 2], w3 = Wc[d * 4 + 3];
    float acc = bc[d];
    const float* base = xr + (size_t)row * (2 * D_INNER) + d;
    const ptrdiff_t st = 2 * D_INNER;
    if (l >= 3) acc = fmaf(base[-3 * st], w0, acc);
    if (l >= 2) acc = fmaf(base[-2 * st], w1, acc);
    if (l >= 1) acc = fmaf(base[-1 * st], w2, acc);
    acc = fmaf(base[0], w3, acc);
    float v = siluf(acc);
    short h, lo; split2(v, h, lo);
    xsh[idx] = h; xsl[idx] = lo;
}

// Sum SK split-K partials -> xdbl fp32; delta cols (<48) also to padded planes (ld 64, pad zeroed).
__global__ __launch_bounds__(256) void reduceK_kernel(
    const float* __restrict__ part, float* __restrict__ xdbl,
    short* __restrict__ xdh, short* __restrict__ xdl, int SK)
{
    int i = blockIdx.x * 256 + threadIdx.x;   // < BL*80
    const size_t st = (size_t)BL * 80;
    float s = 0.f;
    for (int c = 0; c < SK; ++c) s += part[i + c * st];
    xdbl[i] = s;
    int row = i / 80, col = i % 80;
    if (col < 48) {
        short h, l; split2(s, h, l);
        xdh[(size_t)row * 64 + col] = h; xdl[(size_t)row * 64 + col] = l;
    } else if (col < 64) {
        xdh[(size_t)row * 64 + col] = 0; xdl[(size_t)row * 64 + col] = 0;
    }
}

// ---- Chunked parallel scan, 16 states per THREAD ----
__global__ __launch_bounds__(256) void scan_part1(
    const float* __restrict__ xr, const short* __restrict__ xsh,
    const short* __restrict__ xsl, const float* __restrict__ xdbl,
    const float* __restrict__ A_log, float* __restrict__ P, float* __restrict__ S,
    int CL)
{
    const int t = blockIdx.x * 256 + threadIdx.x;
    const int d = t % D_INNER;
    const int cb = t / D_INNER;
    const int b = cb % BATCH;
    const int c = cb / BATCH;
    const int l0 = c * CL;

    float Ac[16];
#pragma unroll
    for (int q = 0; q < 4; ++q) {
        float4 v = ((const float4*)(A_log + d * 16))[q];
        Ac[q*4+0] = -__expf(v.x); Ac[q*4+1] = -__expf(v.y);
        Ac[q*4+2] = -__expf(v.z); Ac[q*4+3] = -__expf(v.w);
    }
    float h[16];
#pragma unroll
    for (int n = 0; n < 16; ++n) h[n] = 0.f;
    float sdt = 0.f;

    const float* dptr = xr   + ((size_t)b * SEQ + l0) * (2 * D_INNER) + d;
    size_t xoff       = ((size_t)b * SEQ + l0) * D_INNER + d;
    const float* brow = xdbl + ((size_t)b * SEQ + l0) * 80 + DT_RANK;

    for (int l = 0; l < CL; ++l) {
        float dt = *dptr;
        float xt = bf2f(xsh[xoff]) + bf2f(xsl[xoff]);
        float cc = dt * xt;
        float Bv[16];
#pragma unroll
        for (int q = 0; q < 4; ++q) {
            float4 v = ((const float4*)brow)[q];
            Bv[q*4+0]=v.x; Bv[q*4+1]=v.y; Bv[q*4+2]=v.z; Bv[q*4+3]=v.w;
        }
#pragma unroll
        for (int n = 0; n < 16; ++n)
            h[n] = fmaf(__expf(Ac[n] * dt), h[n], cc * Bv[n]);
        sdt += dt;
        dptr += 2 * D_INNER; xoff += D_INNER; brow += 80;
    }
#pragma unroll
    for (int n = 0; n < 16; ++n) {
        P[(size_t)t * 16 + n] = __expf(Ac[n] * sdt);
        S[(size_t)t * 16 + n] = h[n];
    }
}

__global__ __launch_bounds__(256) void scan_combine(
    const float* __restrict__ P, const float* __restrict__ S,
    float* __restrict__ Hin, int NC)
{
    const int j = blockIdx.x * 256 + threadIdx.x;   // < NSTATE_TOT
    float h = 0.f;
    for (int c = 0; c < NC; ++c) {
        size_t idx = (size_t)c * NSTATE_TOT + j;
        Hin[idx] = h;
        h = fmaf(P[idx], h, S[idx]);
    }
}

// Re-scan from Hin; y = (h·C + xt*D)*silu(res) -> hi/lo planes in-place over xs planes.
__global__ __launch_bounds__(256) void scan_part2(
    const float* __restrict__ xr, const float* __restrict__ xdbl,
    const float* __restrict__ A_log, const float* __restrict__ Dvec,
    const float* __restrict__ Hin, short* __restrict__ xsh, short* __restrict__ xsl,
    int CL)
{
    const int t = blockIdx.x * 256 + threadIdx.x;
    const int d = t % D_INNER;
    const int cb = t / D_INNER;
    const int b = cb % BATCH;
    const int c = cb / BATCH;
    const int l0 = c * CL;

    float Ac[16];
#pragma unroll
    for (int q = 0; q < 4; ++q) {
        float4 v = ((const float4*)(A_log + d * 16))[q];
        Ac[q*4+0] = -__expf(v.x); Ac[q*4+1] = -__expf(v.y);
        Ac[q*4+2] = -__expf(v.z); Ac[q*4+3] = -__expf(v.w);
    }
    const float Dd = Dvec[d];
    float h[16];
#pragma unroll
    for (int q = 0; q < 4; ++q) {
        float4 v = ((const float4*)(Hin + (size_t)t * 16))[q];
        h[q*4+0]=v.x; h[q*4+1]=v.y; h[q*4+2]=v.z; h[q*4+3]=v.w;
    }

    const float* dptr = xr   + ((size_t)b * SEQ + l0) * (2 * D_INNER) + d;
    const float* rptr = dptr + D_INNER;
    const float* brow = xdbl + ((size_t)b * SEQ + l0) * 80 + DT_RANK;
    size_t xoff       = ((size_t)b * SEQ + l0) * D_INNER + d;

    for (int l = 0; l < CL; ++l) {
        float dt = *dptr;
        float xt = bf2f(xsh[xoff]) + bf2f(xsl[xoff]);
        float res = *rptr;
        float cc = dt * xt;
        float Bv[16], Cv[16];
#pragma unroll
        for (int q = 0; q < 4; ++q) {
            float4 v = ((const float4*)brow)[q];
            Bv[q*4+0]=v.x; Bv[q*4+1]=v.y; Bv[q*4+2]=v.z; Bv[q*4+3]=v.w;
            float4 w = ((const float4*)brow)[q + 4];
            Cv[q*4+0]=w.x; Cv[q*4+1]=w.y; Cv[q*4+2]=w.z; Cv[q*4+3]=w.w;
        }
#pragma unroll
        for (int n = 0; n < 16; ++n)
            h[n] = fmaf(__expf(Ac[n] * dt), h[n], cc * Bv[n]);
        float y0 = 0.f, y1 = 0.f, y2 = 0.f, y3 = 0.f;
#pragma unroll
        for (int n = 0; n < 4; ++n) {
            y0 = fmaf(h[n],      Cv[n],      y0);
            y1 = fmaf(h[n + 4],  Cv[n + 4],  y1);
            y2 = fmaf(h[n + 8],  Cv[n + 8],  y2);
            y3 = fmaf(h[n + 12], Cv[n + 12], y3);
        }
        float y = ((y0 + y1) + (y2 + y3)) + xt * Dd;
        y *= siluf(res);
        short hh, ll; split2(y, hh, ll);
        xsh[xoff] = hh; xsl[xoff] = ll;
        dptr += 2 * D_INNER; rptr += 2 * D_INNER; brow += 80; xoff += D_INNER;
    }
}

extern "C" void kernel_launch(void* const* d_in, const int* in_sizes, int n_in,
                              void* d_out, int out_size, void* d_ws, size_t ws_size,
                              hipStream_t stream) {
    const float* x      = (const float*)d_in[0];
    const float* W_in   = (const float*)d_in[1];
    const float* W_conv = (const float*)d_in[2];
    const float* b_conv = (const float*)d_in[3];
    const float* W_xproj= (const float*)d_in[4];
    const float* W_dt   = (const float*)d_in[5];
    const float* b_dt   = (const float*)d_in[6];
    const float* A_log  = (const float*)d_in[7];
    const float* Dv     = (const float*)d_in[8];
    const float* W_out  = (const float*)d_in[9];
    float* out = (float*)d_out;

    // ---- workspace layout ----
    char* base = (char*)d_ws;
    size_t off = 0;
    auto alloc = [&](size_t bytes) { char* p = base + off; off += (bytes + 255) & ~(size_t)255; return p; };

    float* xr   = (float*)alloc((size_t)BL * 3072 * 4);          // in_proj out (delta overwrites cols 0-1535)
    short* xsh  = (short*)alloc((size_t)BL * 1536 * 2);          // x-planes -> xs planes -> y planes
    short* xsl  = (short*)alloc((size_t)BL * 1536 * 2);
    float* xdbl = (float*)alloc((size_t)BL * 80 * 4);
    short* xdh  = (short*)alloc((size_t)BL * 64 * 2);            // delta input planes, K padded to 64
    short* xdl  = (short*)alloc((size_t)BL * 64 * 2);
    short* wxh  = (short*)alloc((size_t)80 * 1536 * 2);
    short* wxl  = (short*)alloc((size_t)80 * 1536 * 2);
    short* wdth = (short*)alloc((size_t)1536 * 64 * 2);          // padded to 64
    short* wdtl = (short*)alloc((size_t)1536 * 64 * 2);
    short* woh  = (short*)alloc((size_t)768 * 1536 * 2);
    short* wol  = (short*)alloc((size_t)768 * 1536 * 2);
    size_t fixed_end = off;
    size_t region_avail = ws_size > fixed_end ? ws_size - fixed_end : 0;

    // Time-disjoint region: {W_in planes} -> {split-K partials} -> {P/S/Hin}
    char* region = base + fixed_end;
    short* winh = (short*)region;
    short* winl = winh + (size_t)3072 * 768;
    float* part = (float*)region;
    int SK = (region_avail >= 8ull * BL * 80 * 4) ? 8 : 4;
    int NC = 2;
    for (int cand = 64; cand >= 2; cand >>= 1) {
        if (3ull * cand * NSTATE_TOT * 4 <= region_avail) { NC = cand; break; }
    }
    float* P    = (float*)region;
    float* S    = P + (size_t)NC * NSTATE_TOT;
    float* Hin  = S + (size_t)NC * NSTATE_TOT;
    const int CL = SEQ / NC;

    dim3 blk(256);

    // 0) pre-split operands to bf16 hi/lo planes
    split_f32<<<dim3(BL * 768 / 8 / 256), blk, 0, stream>>>(x, xsh, xsl, BL * 768 / 8);          // x planes (reuse xs bufs)
    split_f32<<<dim3(3072 * 768 / 8 / 256), blk, 0, stream>>>(W_in, winh, winl, 3072 * 768 / 8);
    split_f32<<<dim3(80 * 1536 / 8 / 256), blk, 0, stream>>>(W_xproj, wxh, wxl, 80 * 1536 / 8);
    split_f32<<<dim3(768 * 1536 / 8 / 256), blk, 0, stream>>>(W_out, woh, wol, 768 * 1536 / 8);
    split_pad_kernel<<<dim3(1536 * 64 / 256), blk, 0, stream>>>(W_dt, wdth, wdtl, 1536, 48, 64);

    // 1) in_proj: xr = x @ W_in^T   (4096x3072, K=768) — 768 blocks
    gemm_g<128, 128, 64, 64, 0><<<dim3(BL / 128, 3072 / 128, 1), blk, 0, stream>>>(
        xsh, xsl, winh, winl, nullptr, xr, BL, 3072, 768, 768, 768, 3072, 768, 0);

    // 2) conv + SiLU -> xs planes (overwrites x planes; safe, in_proj done)
    conv_silu_kernel<<<dim3((BL * D_INNER) / 256), blk, 0, stream>>>(xr, W_conv, b_conv, xsh, xsl);

    // 3) x_proj split-K -> partials, then reduce -> xdbl + padded delta planes
    gemm_g<64, 80, 16, 80, 0><<<dim3(BL / 64, 1, SK), blk, 0, stream>>>(
        xsh, xsl, wxh, wxl, nullptr, part, BL, 80, 1536, 1536, 1536, 80, 1536 / SK, (long long)BL * 80);
    reduceK_kernel<<<dim3(BL * 80 / 256), blk, 0, stream>>>(part, xdbl, xdh, xdl, SK);

    // 4) delta = softplus(xd @ W_dt^T + b_dt) -> xr cols [0,1536)  (K padded to 64) — 1536 blocks
    gemm_g<64, 64, 32, 32, 1><<<dim3(BL / 64, 1536 / 64, 1), blk, 0, stream>>>(
        xdh, xdl, wdth, wdtl, b_dt, xr, BL, 1536, 64, 64, 64, 3072, 64, 0);

    // 5) chunked scan; gated y written as hi/lo planes in-place over xs planes
    scan_part1<<<dim3(NC * BATCH * D_INNER / 256), blk, 0, stream>>>(
        xr, xsh, xsl, xdbl, A_log, P, S, CL);
    scan_combine<<<dim3(NSTATE_TOT / 256), blk, 0, stream>>>(P, S, Hin, NC);
    scan_part2<<<dim3(NC * BATCH * D_INNER / 256), blk, 0, stream>>>(
        xr, xdbl, A_log, Dv, Hin, xsh, xsl, CL);

    // 6) out_proj: out = y @ W_out^T  (4096x768, K=1536) — 768 blocks
    gemm_g<64, 64, 32, 32, 0><<<dim3(BL / 64, 768 / 64, 1), blk, 0, stream>>>(
        xsh, xsl, woh, wol, nullptr, out, BL, 768, 1536, 1536, 1536, 768, 1536, 0);
}

// Round 8
// 252.688 us; speedup vs baseline: 4.2578x; 1.0948x over previous
//
#include <hip/hip_runtime.h>
#include <hip/hip_bf16.h>
#include <cmath>

#define D_MODEL 768
#define D_INNER 1536
#define DT_RANK 48
#define D_STATE 16
#define D_CONV  4
#define BATCH   2
#define SEQ     2048
#define BL      (BATCH * SEQ)
#define NSTATE_TOT (BATCH * D_INNER * D_STATE)   // 49152

typedef __attribute__((ext_vector_type(8))) _Float16 half8;
typedef __attribute__((ext_vector_type(8))) short short8;
typedef __attribute__((ext_vector_type(4))) float f32x4;

__device__ __forceinline__ float siluf(float x) { return x / (1.f + __expf(-x)); }
__device__ __forceinline__ float softplusf(float x) {
    return (x > 20.f) ? x : log1pf(__expf(x));
}

// fp32 -> (hi, lo) fp16 pair (RNE). x ≈ hi + lo to ~2^-22 rel.
__device__ __forceinline__ void split2h(float x, short& hi, short& lo) {
    _Float16 h = (_Float16)x;
    _Float16 l = (_Float16)(x - (float)h);
    hi = *(short*)&h; lo = *(short*)&l;
}
__device__ __forceinline__ short f2h(float x) {
    _Float16 h = (_Float16)x; return *(short*)&h;
}
__device__ __forceinline__ float h2f(short s) {
    _Float16 h; *(short*)&h = s; return (float)h;
}

// async global->LDS, 16 bytes per lane. LDS dest is wave-uniform base + lane*16.
__device__ __forceinline__ void gload16(const void* g, void* l) {
    __builtin_amdgcn_global_load_lds(
        (const __attribute__((address_space(1))) void*)g,
        (__attribute__((address_space(3))) void*)l, 16, 0, 0);
}

// fp32 -> fp16 hi/lo planes (8 elems per thread). For activations.
__global__ __launch_bounds__(256) void split_x2(
    const float* __restrict__ src, short* __restrict__ h, short* __restrict__ l,
    int ngroups)
{
    int gi = blockIdx.x * 256 + threadIdx.x;
    if (gi >= ngroups) return;
    const float* p = src + (size_t)gi * 8;
    float4 a = ((const float4*)p)[0];
    float4 b = ((const float4*)p)[1];
    float xv[8] = {a.x, a.y, a.z, a.w, b.x, b.y, b.z, b.w};
    short8 vh, vl;
#pragma unroll
    for (int e = 0; e < 8; ++e) { short hh, ll; split2h(xv[e], hh, ll); vh[e] = hh; vl[e] = ll; }
    *(short8*)(h + (size_t)gi * 8) = vh;
    *(short8*)(l + (size_t)gi * 8) = vl;
}

// Fused weight conversion: fp32 -> single fp16 plane for W_in, W_xproj, W_out.
#define GIN  (3072 * 768 / 8)
#define GX   (80 * 1536 / 8)
#define GOUT (768 * 1536 / 8)
__global__ __launch_bounds__(256) void cvt_weights(
    const float* __restrict__ win, const float* __restrict__ wx,
    const float* __restrict__ wout, short* __restrict__ oin,
    short* __restrict__ ox, short* __restrict__ oout)
{
    int gi = blockIdx.x * 256 + threadIdx.x;
    const float* s; short* d; int li;
    if (gi < GIN)            { s = win;  d = oin;  li = gi; }
    else if (gi < GIN + GX)  { s = wx;   d = ox;   li = gi - GIN; }
    else if (gi < GIN + GX + GOUT) { s = wout; d = oout; li = gi - GIN - GX; }
    else return;
    const float* p = s + (size_t)li * 8;
    float4 a = ((const float4*)p)[0];
    float4 b = ((const float4*)p)[1];
    float xv[8] = {a.x, a.y, a.z, a.w, b.x, b.y, b.z, b.w};
    short8 vh;
#pragma unroll
    for (int e = 0; e < 8; ++e) vh[e] = f2h(xv[e]);
    *(short8*)(d + (size_t)li * 8) = vh;
}

// W_dt [1536][48] fp32 -> single fp16 plane [1536][64], cols 48-63 zero.
__global__ __launch_bounds__(256) void cvt_pad_dt(
    const float* __restrict__ src, short* __restrict__ h)
{
    int i = blockIdx.x * 256 + threadIdx.x;
    if (i >= 1536 * 64) return;
    int r = i >> 6, c = i & 63;
    h[i] = (c < 48) ? f2h(src[r * 48 + c]) : (short)0;
}

// Stage one fp16 plane tile [ROWS][32] into linear LDS via global_load_lds.
// Pre-swizzled source: LDS slot (r, j) holds k-group j ^ ((r>>1)&3).
template<int ROWS>
__device__ __forceinline__ void stage_plane(
    const short* __restrict__ gp, int ldk, short* lds, int wid, int lane)
{
    constexpr int CH = ROWS / 16;            // 1KB chunks (16 rows x 64B)
    const int rr = lane >> 2, jj = lane & 3;
    for (int c = wid; c < CH; c += 4) {
        int r = c * 16 + rr;
        int kg = jj ^ ((r >> 1) & 3);
        gload16(gp + (size_t)r * ldk + kg * 8, lds + c * 512);
    }
}

// C[M,N] = A[M,K] @ Bw[N,K]^T, fp16 2-term MFMA (A = hi+lo planes, B = hi plane).
// K (and klen) multiples of 32. Split-K via blockIdx.z.
// EPI==1: C = softplus(C + bias[n]).
template<int BM, int BN, int WM, int WN, int EPI>
__global__ __launch_bounds__(256) void gemm_g(
    const short* __restrict__ Ah, const short* __restrict__ Al,
    const short* __restrict__ Bh,
    const float* __restrict__ bias, float* __restrict__ C,
    int M, int N, int K, int lda, int ldb, int ldc, int klen, long long pstride)
{
    constexpr int NWM = BM / WM, NWN = BN / WN;
    static_assert(NWM * NWN == 4, "4 waves");
    constexpr int FM = WM / 16, FN = WN / 16;

    __shared__ short sAh[BM * 32], sAl[BM * 32];
    __shared__ short sBh[BN * 32];

    const int tid = threadIdx.x, lane = tid & 63, wid = tid >> 6;
    const int bm0 = blockIdx.x * BM, bn0 = blockIdx.y * BN;
    const int kbeg = blockIdx.z * klen;
    const int kend = min(K, kbeg + klen);
    float* Cp = C + (long long)blockIdx.z * pstride;
    const int wm0 = (wid / NWN) * WM, wn0 = (wid % NWN) * WN;

    const short* Aht = Ah + (size_t)bm0 * lda;
    const short* Alt = Al + (size_t)bm0 * lda;
    const short* Bht = Bh + (size_t)bn0 * ldb;

    f32x4 acc[FM][FN];
#pragma unroll
    for (int i = 0; i < FM; ++i)
#pragma unroll
        for (int j = 0; j < FN; ++j)
            acc[i][j] = (f32x4){0.f, 0.f, 0.f, 0.f};

    const int rsel = lane & 15;
    const int kg = lane >> 4;       // k-group (8 halves each)

    for (int k0 = kbeg; k0 < kend; k0 += 32) {
        stage_plane<BM>(Aht + k0, lda, sAh, wid, lane);
        stage_plane<BM>(Alt + k0, lda, sAl, wid, lane);
        stage_plane<BN>(Bht + k0, ldb, sBh, wid, lane);
        __syncthreads();            // drains vmcnt then barrier

        half8 afh[FM], afl[FM], bfh[FN];
#pragma unroll
        for (int i = 0; i < FM; ++i) {
            int row = wm0 + i * 16 + rsel;
            int off = row * 32 + ((kg ^ ((row >> 1) & 3)) << 3);
            afh[i] = *(const half8*)(sAh + off);
            afl[i] = *(const half8*)(sAl + off);
        }
#pragma unroll
        for (int j = 0; j < FN; ++j) {
            int row = wn0 + j * 16 + rsel;
            int off = row * 32 + ((kg ^ ((row >> 1) & 3)) << 3);
            bfh[j] = *(const half8*)(sBh + off);
        }
#pragma unroll
        for (int i = 0; i < FM; ++i)
#pragma unroll
            for (int j = 0; j < FN; ++j) {
                acc[i][j] = __builtin_amdgcn_mfma_f32_16x16x32_f16(afl[i], bfh[j], acc[i][j], 0, 0, 0);
                acc[i][j] = __builtin_amdgcn_mfma_f32_16x16x32_f16(afh[i], bfh[j], acc[i][j], 0, 0, 0);
            }
        __syncthreads();            // protect LDS from next stage
    }

    const int r0 = bm0 + wm0 + (lane >> 4) * 4;
    const int c0 = bn0 + wn0 + rsel;
#pragma unroll
    for (int i = 0; i < FM; ++i)
#pragma unroll
        for (int j = 0; j < FN; ++j) {
            int c = c0 + j * 16;
            if (c >= N) continue;
#pragma unroll
            for (int q = 0; q < 4; ++q) {
                int r = r0 + i * 16 + q;
                float v = acc[i][j][q];
                if (EPI == 1) { v += bias[c]; v = softplusf(v); }
                Cp[(size_t)r * ldc + c] = v;
            }
        }
}

// Causal depthwise conv (K=4) + bias + SiLU -> fp16 hi/lo planes.
__global__ __launch_bounds__(256) void conv_silu_kernel(
    const float* __restrict__ xr, const float* __restrict__ Wc,
    const float* __restrict__ bc, short* __restrict__ xsh, short* __restrict__ xsl)
{
    int idx = blockIdx.x * 256 + threadIdx.x;
    int d   = idx % D_INNER;
    int row = idx / D_INNER;
    int l   = row % SEQ;
    float w0 = Wc[d * 4 + 0], w1 = Wc[d * 4 + 1];
    float w2 = Wc[d * 4 + 2], w3 = Wc[d * 4 + 3];
    float acc = bc[d];
    const float* base = xr + (size_t)row * (2 * D_INNER) + d;
    const ptrdiff_t st = 2 * D_INNER;
    if (l >= 3) acc = fmaf(base[-3 * st], w0, acc);
    if (l >= 2) acc = fmaf(base[-2 * st], w1, acc);
    if (l >= 1) acc = fmaf(base[-1 * st], w2, acc);
    acc = fmaf(base[0], w3, acc);
    float v = siluf(acc);
    short h, lo; split2h(v, h, lo);
    xsh[idx] = h; xsl[idx] = lo;
}

// Sum SK split-K partials -> xdbl fp32; delta cols(<48) to fp16 planes padded to 64.
__global__ __launch_bounds__(256) void reduceK_kernel(
    const float* __restrict__ part, float* __restrict__ xdbl,
    short* __restrict__ xdh, short* __restrict__ xdl, int SK)
{
    int i = blockIdx.x * 256 + threadIdx.x;   // < BL*80
    const size_t st = (size_t)BL * 80;
    float s = 0.f;
    for (int c = 0; c < SK; ++c) s += part[i + c * st];
    xdbl[i] = s;
    int row = i / 80, col = i % 80;
    if (col < 48) {
        short h, l; split2h(s, h, l);
        xdh[(size_t)row * 64 + col] = h; xdl[(size_t)row * 64 + col] = l;
    } else if (col < 64) {
        xdh[(size_t)row * 64 + col] = 0; xdl[(size_t)row * 64 + col] = 0;
    }
}

// ---- Chunked parallel scan, 16 states per THREAD ----
__global__ __launch_bounds__(256) void scan_part1(
    const float* __restrict__ xr, const short* __restrict__ xsh,
    const short* __restrict__ xsl, const float* __restrict__ xdbl,
    const float* __restrict__ A_log, float* __restrict__ P, float* __restrict__ S,
    int CL)
{
    const int t = blockIdx.x * 256 + threadIdx.x;
    const int d = t % D_INNER;
    const int cb = t / D_INNER;
    const int b = cb % BATCH;
    const int c = cb / BATCH;
    const int l0 = c * CL;

    float Ac[16];
#pragma unroll
    for (int q = 0; q < 4; ++q) {
        float4 v = ((const float4*)(A_log + d * 16))[q];
        Ac[q*4+0] = -__expf(v.x); Ac[q*4+1] = -__expf(v.y);
        Ac[q*4+2] = -__expf(v.z); Ac[q*4+3] = -__expf(v.w);
    }
    float h[16];
#pragma unroll
    for (int n = 0; n < 16; ++n) h[n] = 0.f;
    float sdt = 0.f;

    const float* dptr = xr   + ((size_t)b * SEQ + l0) * (2 * D_INNER) + d;
    size_t xoff       = ((size_t)b * SEQ + l0) * D_INNER + d;
    const float* brow = xdbl + ((size_t)b * SEQ + l0) * 80 + DT_RANK;

    for (int l = 0; l < CL; ++l) {
        float dt = *dptr;
        float xt = h2f(xsh[xoff]) + h2f(xsl[xoff]);
        float cc = dt * xt;
        float Bv[16];
#pragma unroll
        for (int q = 0; q < 4; ++q) {
            float4 v = ((const float4*)brow)[q];
            Bv[q*4+0]=v.x; Bv[q*4+1]=v.y; Bv[q*4+2]=v.z; Bv[q*4+3]=v.w;
        }
#pragma unroll
        for (int n = 0; n < 16; ++n)
            h[n] = fmaf(__expf(Ac[n] * dt), h[n], cc * Bv[n]);
        sdt += dt;
        dptr += 2 * D_INNER; xoff += D_INNER; brow += 80;
    }
#pragma unroll
    for (int n = 0; n < 16; ++n) {
        P[(size_t)t * 16 + n] = __expf(Ac[n] * sdt);
        S[(size_t)t * 16 + n] = h[n];
    }
}

__global__ __launch_bounds__(256) void scan_combine(
    const float* __restrict__ P, const float* __restrict__ S,
    float* __restrict__ Hin, int NC)
{
    const int j = blockIdx.x * 256 + threadIdx.x;   // < NSTATE_TOT
    float h = 0.f;
    for (int c = 0; c < NC; ++c) {
        size_t idx = (size_t)c * NSTATE_TOT + j;
        Hin[idx] = h;
        h = fmaf(P[idx], h, S[idx]);
    }
}

// Re-scan from Hin; y = (h·C + xt*D)*silu(res) -> fp16 planes in-place over xs planes.
__global__ __launch_bounds__(256) void scan_part2(
    const float* __restrict__ xr, const float* __restrict__ xdbl,
    const float* __restrict__ A_log, const float* __restrict__ Dvec,
    const float* __restrict__ Hin, short* __restrict__ xsh, short* __restrict__ xsl,
    int CL)
{
    const int t = blockIdx.x * 256 + threadIdx.x;
    const int d = t % D_INNER;
    const int cb = t / D_INNER;
    const int b = cb % BATCH;
    const int c = cb / BATCH;
    const int l0 = c * CL;

    float Ac[16];
#pragma unroll
    for (int q = 0; q < 4; ++q) {
        float4 v = ((const float4*)(A_log + d * 16))[q];
        Ac[q*4+0] = -__expf(v.x); Ac[q*4+1] = -__expf(v.y);
        Ac[q*4+2] = -__expf(v.z); Ac[q*4+3] = -__expf(v.w);
    }
    const float Dd = Dvec[d];
    float h[16];
#pragma unroll
    for (int q = 0; q < 4; ++q) {
        float4 v = ((const float4*)(Hin + (size_t)t * 16))[q];
        h[q*4+0]=v.x; h[q*4+1]=v.y; h[q*4+2]=v.z; h[q*4+3]=v.w;
    }

    const float* dptr = xr   + ((size_t)b * SEQ + l0) * (2 * D_INNER) + d;
    const float* rptr = dptr + D_INNER;
    const float* brow = xdbl + ((size_t)b * SEQ + l0) * 80 + DT_RANK;
    size_t xoff       = ((size_t)b * SEQ + l0) * D_INNER + d;

    for (int l = 0; l < CL; ++l) {
        float dt = *dptr;
        float xt = h2f(xsh[xoff]) + h2f(xsl[xoff]);
        float res = *rptr;
        float cc = dt * xt;
        float Bv[16], Cv[16];
#pragma unroll
        for (int q = 0; q < 4; ++q) {
            float4 v = ((const float4*)brow)[q];
            Bv[q*4+0]=v.x; Bv[q*4+1]=v.y; Bv[q*4+2]=v.z; Bv[q*4+3]=v.w;
            float4 w = ((const float4*)brow)[q + 4];
            Cv[q*4+0]=w.x; Cv[q*4+1]=w.y; Cv[q*4+2]=w.z; Cv[q*4+3]=w.w;
        }
#pragma unroll
        for (int n = 0; n < 16; ++n)
            h[n] = fmaf(__expf(Ac[n] * dt), h[n], cc * Bv[n]);
        float y0 = 0.f, y1 = 0.f, y2 = 0.f, y3 = 0.f;
#pragma unroll
        for (int n = 0; n < 4; ++n) {
            y0 = fmaf(h[n],      Cv[n],      y0);
            y1 = fmaf(h[n + 4],  Cv[n + 4],  y1);
            y2 = fmaf(h[n + 8],  Cv[n + 8],  y2);
            y3 = fmaf(h[n + 12], Cv[n + 12], y3);
        }
        float y = ((y0 + y1) + (y2 + y3)) + xt * Dd;
        y *= siluf(res);
        short hh, ll; split2h(y, hh, ll);
        xsh[xoff] = hh; xsl[xoff] = ll;
        dptr += 2 * D_INNER; rptr += 2 * D_INNER; brow += 80; xoff += D_INNER;
    }
}

extern "C" void kernel_launch(void* const* d_in, const int* in_sizes, int n_in,
                              void* d_out, int out_size, void* d_ws, size_t ws_size,
                              hipStream_t stream) {
    const float* x      = (const float*)d_in[0];
    const float* W_in   = (const float*)d_in[1];
    const float* W_conv = (const float*)d_in[2];
    const float* b_conv = (const float*)d_in[3];
    const float* W_xproj= (const float*)d_in[4];
    const float* W_dt   = (const float*)d_in[5];
    const float* b_dt   = (const float*)d_in[6];
    const float* A_log  = (const float*)d_in[7];
    const float* Dv     = (const float*)d_in[8];
    const float* W_out  = (const float*)d_in[9];
    float* out = (float*)d_out;

    // ---- workspace layout ----
    char* base = (char*)d_ws;
    size_t off = 0;
    auto alloc = [&](size_t bytes) { char* p = base + off; off += (bytes + 255) & ~(size_t)255; return p; };

    float* xr   = (float*)alloc((size_t)BL * 3072 * 4);          // in_proj out (delta overwrites cols 0-1535)
    short* xsh  = (short*)alloc((size_t)BL * 1536 * 2);          // x-planes -> xs planes -> y planes
    short* xsl  = (short*)alloc((size_t)BL * 1536 * 2);
    float* xdbl = (float*)alloc((size_t)BL * 80 * 4);
    short* xdh  = (short*)alloc((size_t)BL * 64 * 2);            // delta input planes, K padded to 64
    short* xdl  = (short*)alloc((size_t)BL * 64 * 2);
    short* wxh  = (short*)alloc((size_t)80 * 1536 * 2);          // weight hi planes only
    short* wdth = (short*)alloc((size_t)1536 * 64 * 2);
    short* woh  = (short*)alloc((size_t)768 * 1536 * 2);
    size_t fixed_end = off;
    size_t region_avail = ws_size > fixed_end ? ws_size - fixed_end : 0;

    // Time-disjoint region: {W_in plane} -> {split-K partials} -> {P/S/Hin}
    char* region = base + fixed_end;
    short* winh = (short*)region;
    float* part = (float*)region;
    int SK = (region_avail >= 8ull * BL * 80 * 4) ? 8 : 4;
    int NC = 2;
    for (int cand = 64; cand >= 2; cand >>= 1) {
        if (3ull * cand * NSTATE_TOT * 4 <= region_avail) { NC = cand; break; }
    }
    float* P    = (float*)region;
    float* S    = P + (size_t)NC * NSTATE_TOT;
    float* Hin  = S + (size_t)NC * NSTATE_TOT;
    const int CL = SEQ / NC;

    dim3 blk(256);

    // 0) operand prep: x -> 2 fp16 planes; weights -> 1 fp16 plane each
    split_x2<<<dim3(BL * 768 / 8 / 256), blk, 0, stream>>>(x, xsh, xsl, BL * 768 / 8);
    cvt_weights<<<dim3((GIN + GX + GOUT + 255) / 256), blk, 0, stream>>>(
        W_in, W_xproj, W_out, winh, wxh, woh);
    cvt_pad_dt<<<dim3(1536 * 64 / 256), blk, 0, stream>>>(W_dt, wdth);

    // 1) in_proj: xr = x @ W_in^T   (4096x3072, K=768) — 768 blocks
    gemm_g<128, 128, 64, 64, 0><<<dim3(BL / 128, 3072 / 128, 1), blk, 0, stream>>>(
        xsh, xsl, winh, nullptr, xr, BL, 3072, 768, 768, 768, 3072, 768, 0);

    // 2) conv + SiLU -> xs planes (overwrites x planes; safe, in_proj done)
    conv_silu_kernel<<<dim3((BL * D_INNER) / 256), blk, 0, stream>>>(xr, W_conv, b_conv, xsh, xsl);

    // 3) x_proj split-K -> partials, then reduce -> xdbl + padded delta planes
    gemm_g<64, 80, 16, 80, 0><<<dim3(BL / 64, 1, SK), blk, 0, stream>>>(
        xsh, xsl, wxh, nullptr, part, BL, 80, 1536, 1536, 1536, 80, 1536 / SK, (long long)BL * 80);
    reduceK_kernel<<<dim3(BL * 80 / 256), blk, 0, stream>>>(part, xdbl, xdh, xdl, SK);

    // 4) delta = softplus(xd @ W_dt^T + b_dt) -> xr cols [0,1536)  (K padded to 64)
    gemm_g<64, 64, 32, 32, 1><<<dim3(BL / 64, 1536 / 64, 1), blk, 0, stream>>>(
        xdh, xdl, wdth, b_dt, xr, BL, 1536, 64, 64, 64, 3072, 64, 0);

    // 5) chunked scan; gated y written as fp16 planes in-place over xs planes
    scan_part1<<<dim3(NC * BATCH * D_INNER / 256), blk, 0, stream>>>(
        xr, xsh, xsl, xdbl, A_log, P, S, CL);
    scan_combine<<<dim3(NSTATE_TOT / 256), blk, 0, stream>>>(P, S, Hin, NC);
    scan_part2<<<dim3(NC * BATCH * D_INNER / 256), blk, 0, stream>>>(
        xr, xdbl, A_log, Dv, Hin, xsh, xsl, CL);

    // 6) out_proj: out = y @ W_out^T  (4096x768, K=1536) — 768 blocks
    gemm_g<64, 64, 32, 32, 0><<<dim3(BL / 64, 768 / 64, 1), blk, 0, stream>>>(
        xsh, xsl, woh, nullptr, out, BL, 768, 1536, 1536, 1536, 768, 1536, 0);
}

// Round 9
// 227.241 us; speedup vs baseline: 4.7346x; 1.1120x over previous
//
#include <hip/hip_runtime.h>
#include <hip/hip_bf16.h>
#include <cmath>

#define D_MODEL 768
#define D_INNER 1536
#define DT_RANK 48
#define D_STATE 16
#define D_CONV  4
#define BATCH   2
#define SEQ     2048
#define BL      (BATCH * SEQ)
#define NSTATE_TOT (BATCH * D_INNER * D_STATE)   // 49152

typedef __attribute__((ext_vector_type(8))) _Float16 half8;
typedef __attribute__((ext_vector_type(8))) short short8;
typedef __attribute__((ext_vector_type(4))) float f32x4;

__device__ __forceinline__ float siluf(float x) { return x / (1.f + __expf(-x)); }
__device__ __forceinline__ float softplusf(float x) {
    return (x > 20.f) ? x : log1pf(__expf(x));
}

__device__ __forceinline__ void split2h(float x, short& hi, short& lo) {
    _Float16 h = (_Float16)x;
    _Float16 l = (_Float16)(x - (float)h);
    hi = *(short*)&h; lo = *(short*)&l;
}
__device__ __forceinline__ short f2h(float x) {
    _Float16 h = (_Float16)x; return *(short*)&h;
}
__device__ __forceinline__ float h2f(short s) {
    _Float16 h; *(short*)&h = s; return (float)h;
}

// async global->LDS, 16 bytes per lane.
__device__ __forceinline__ void gload16(const void* g, void* l) {
    __builtin_amdgcn_global_load_lds(
        (const __attribute__((address_space(1))) void*)g,
        (__attribute__((address_space(3))) void*)l, 16, 0, 0);
}

// Fused fp32 -> single fp16 plane conversion: x, W_in, W_xproj, W_out.
#define GXIN (BL * 768 / 8)
#define GIN  (3072 * 768 / 8)
#define GX   (80 * 1536 / 8)
#define GOUT (768 * 1536 / 8)
__global__ __launch_bounds__(256) void cvt_all(
    const float* __restrict__ x, const float* __restrict__ win,
    const float* __restrict__ wx, const float* __restrict__ wout,
    short* __restrict__ oxh, short* __restrict__ oin,
    short* __restrict__ ox, short* __restrict__ oout)
{
    int gi = blockIdx.x * 256 + threadIdx.x;
    const float* s; short* d; int li;
    if (gi < GXIN)                        { s = x;    d = oxh;  li = gi; }
    else if (gi < GXIN + GIN)             { s = win;  d = oin;  li = gi - GXIN; }
    else if (gi < GXIN + GIN + GX)        { s = wx;   d = ox;   li = gi - GXIN - GIN; }
    else if (gi < GXIN + GIN + GX + GOUT) { s = wout; d = oout; li = gi - GXIN - GIN - GX; }
    else return;
    const float* p = s + (size_t)li * 8;
    float4 a = ((const float4*)p)[0];
    float4 b = ((const float4*)p)[1];
    float xv[8] = {a.x, a.y, a.z, a.w, b.x, b.y, b.z, b.w};
    short8 vh;
#pragma unroll
    for (int e = 0; e < 8; ++e) vh[e] = f2h(xv[e]);
    *(short8*)(d + (size_t)li * 8) = vh;
}

// W_dt [1536][48] fp32 -> fp16 plane [1536][64], cols 48-63 zero.
__global__ __launch_bounds__(256) void cvt_pad_dt(
    const float* __restrict__ src, short* __restrict__ h)
{
    int i = blockIdx.x * 256 + threadIdx.x;
    if (i >= 1536 * 64) return;
    int r = i >> 6, c = i & 63;
    h[i] = (c < 48) ? f2h(src[r * 48 + c]) : (short)0;
}

// Stage one fp16 plane tile [ROWS][32] into linear LDS via global_load_lds.
// Pre-swizzled source: LDS slot (r, j) holds k-group j ^ ((r>>1)&3).
template<int ROWS>
__device__ __forceinline__ void stage_plane(
    const short* __restrict__ gp, int ldk, short* lds, int wid, int lane)
{
    constexpr int CH = ROWS / 16;            // 1KB chunks (16 rows x 64B)
    const int rr = lane >> 2, jj = lane & 3;
    for (int c = wid; c < CH; c += 4) {
        int r = c * 16 + rr;
        int kg = jj ^ ((r >> 1) & 3);
        gload16(gp + (size_t)r * ldk + kg * 8, lds + c * 512);
    }
}

// C[M,N] = A[M,K] @ Bw[N,K]^T, single fp16 MFMA, 2-phase double-buffered LDS.
// K (and klen) multiples of 32. Split-K via blockIdx.z.
// EPI==1: C = softplus(C + bias[n]).
template<int BM, int BN, int WM, int WN, int EPI>
__global__ __launch_bounds__(256) void gemm_g(
    const short* __restrict__ Ah, const short* __restrict__ Bh,
    const float* __restrict__ bias, float* __restrict__ C,
    int M, int N, int K, int lda, int ldb, int ldc, int klen, long long pstride)
{
    constexpr int NWM = BM / WM, NWN = BN / WN;
    static_assert(NWM * NWN == 4, "4 waves");
    constexpr int FM = WM / 16, FN = WN / 16;

    __shared__ short sA[2][BM * 32];
    __shared__ short sB[2][BN * 32];

    const int tid = threadIdx.x, lane = tid & 63, wid = tid >> 6;
    const int bm0 = blockIdx.x * BM, bn0 = blockIdx.y * BN;
    const int kbeg = blockIdx.z * klen;
    const int kend = min(K, kbeg + klen);
    float* Cp = C + (long long)blockIdx.z * pstride;
    const int wm0 = (wid / NWN) * WM, wn0 = (wid % NWN) * WN;

    const short* Aht = Ah + (size_t)bm0 * lda;
    const short* Bht = Bh + (size_t)bn0 * ldb;

    f32x4 acc[FM][FN];
#pragma unroll
    for (int i = 0; i < FM; ++i)
#pragma unroll
        for (int j = 0; j < FN; ++j)
            acc[i][j] = (f32x4){0.f, 0.f, 0.f, 0.f};

    const int rsel = lane & 15;
    const int kg = lane >> 4;       // k-group (8 halves each)

    // prologue: stage first K-tile into buffer 0
    stage_plane<BM>(Aht + kbeg, lda, sA[0], wid, lane);
    stage_plane<BN>(Bht + kbeg, ldb, sB[0], wid, lane);
    __syncthreads();

    int cur = 0;
    for (int k0 = kbeg; k0 < kend; k0 += 32) {
        // issue next tile's loads into the other buffer (in flight during compute)
        if (k0 + 32 < kend) {
            stage_plane<BM>(Aht + k0 + 32, lda, sA[cur ^ 1], wid, lane);
            stage_plane<BN>(Bht + k0 + 32, ldb, sB[cur ^ 1], wid, lane);
        }
        half8 af[FM], bf[FN];
#pragma unroll
        for (int i = 0; i < FM; ++i) {
            int row = wm0 + i * 16 + rsel;
            int off = row * 32 + ((kg ^ ((row >> 1) & 3)) << 3);
            af[i] = *(const half8*)(&sA[cur][off]);
        }
#pragma unroll
        for (int j = 0; j < FN; ++j) {
            int row = wn0 + j * 16 + rsel;
            int off = row * 32 + ((kg ^ ((row >> 1) & 3)) << 3);
            bf[j] = *(const half8*)(&sB[cur][off]);
        }
#pragma unroll
        for (int i = 0; i < FM; ++i)
#pragma unroll
            for (int j = 0; j < FN; ++j)
                acc[i][j] = __builtin_amdgcn_mfma_f32_16x16x32_f16(af[i], bf[j], acc[i][j], 0, 0, 0);
        __syncthreads();            // drains next tile's vmcnt + protects LDS
        cur ^= 1;
    }

    const int r0 = bm0 + wm0 + (lane >> 4) * 4;
    const int c0 = bn0 + wn0 + rsel;
#pragma unroll
    for (int i = 0; i < FM; ++i)
#pragma unroll
        for (int j = 0; j < FN; ++j) {
            int c = c0 + j * 16;
            if (c >= N) continue;
#pragma unroll
            for (int q = 0; q < 4; ++q) {
                int r = r0 + i * 16 + q;
                float v = acc[i][j][q];
                if (EPI == 1) { v += bias[c]; v = softplusf(v); }
                Cp[(size_t)r * ldc + c] = v;
            }
        }
}

// Causal depthwise conv (K=4) + bias + SiLU -> fp16 hi/lo planes (scan uses hi+lo).
__global__ __launch_bounds__(256) void conv_silu_kernel(
    const float* __restrict__ xr, const float* __restrict__ Wc,
    const float* __restrict__ bc, short* __restrict__ xsh, short* __restrict__ xsl)
{
    int idx = blockIdx.x * 256 + threadIdx.x;
    int d   = idx % D_INNER;
    int row = idx / D_INNER;
    int l   = row % SEQ;
    float w0 = Wc[d * 4 + 0], w1 = Wc[d * 4 + 1];
    float w2 = Wc[d * 4 + 2], w3 = Wc[d * 4 + 3];
    float acc = bc[d];
    const float* base = xr + (size_t)row * (2 * D_INNER) + d;
    const ptrdiff_t st = 2 * D_INNER;
    if (l >= 3) acc = fmaf(base[-3 * st], w0, acc);
    if (l >= 2) acc = fmaf(base[-2 * st], w1, acc);
    if (l >= 1) acc = fmaf(base[-1 * st], w2, acc);
    acc = fmaf(base[0], w3, acc);
    float v = siluf(acc);
    short h, lo; split2h(v, h, lo);
    xsh[idx] = h; xsl[idx] = lo;
}

// Sum SK split-K partials -> xdbl fp32; delta cols(<48) to fp16 hi plane padded to 64.
__global__ __launch_bounds__(256) void reduceK_kernel(
    const float* __restrict__ part, float* __restrict__ xdbl,
    short* __restrict__ xdh, int SK)
{
    int i = blockIdx.x * 256 + threadIdx.x;   // < BL*80
    const size_t st = (size_t)BL * 80;
    float s = 0.f;
    for (int c = 0; c < SK; ++c) s += part[i + c * st];
    xdbl[i] = s;
    int row = i / 80, col = i % 80;
    if (col < 48) {
        xdh[(size_t)row * 64 + col] = f2h(s);
    } else if (col < 64) {
        xdh[(size_t)row * 64 + col] = 0;
    }
}

// ---- Chunked parallel scan, 16 states per THREAD ----
__global__ __launch_bounds__(256) void scan_part1(
    const float* __restrict__ xr, const short* __restrict__ xsh,
    const short* __restrict__ xsl, const float* __restrict__ xdbl,
    const float* __restrict__ A_log, float* __restrict__ P, float* __restrict__ S,
    int CL)
{
    const int t = blockIdx.x * 256 + threadIdx.x;
    const int d = t % D_INNER;
    const int cb = t / D_INNER;
    const int b = cb % BATCH;
    const int c = cb / BATCH;
    const int l0 = c * CL;

    float Ac[16];
#pragma unroll
    for (int q = 0; q < 4; ++q) {
        float4 v = ((const float4*)(A_log + d * 16))[q];
        Ac[q*4+0] = -__expf(v.x); Ac[q*4+1] = -__expf(v.y);
        Ac[q*4+2] = -__expf(v.z); Ac[q*4+3] = -__expf(v.w);
    }
    float h[16];
#pragma unroll
    for (int n = 0; n < 16; ++n) h[n] = 0.f;
    float sdt = 0.f;

    const float* dptr = xr   + ((size_t)b * SEQ + l0) * (2 * D_INNER) + d;
    size_t xoff       = ((size_t)b * SEQ + l0) * D_INNER + d;
    const float* brow = xdbl + ((size_t)b * SEQ + l0) * 80 + DT_RANK;

    for (int l = 0; l < CL; ++l) {
        float dt = *dptr;
        float xt = h2f(xsh[xoff]) + h2f(xsl[xoff]);
        float cc = dt * xt;
        float Bv[16];
#pragma unroll
        for (int q = 0; q < 4; ++q) {
            float4 v = ((const float4*)brow)[q];
            Bv[q*4+0]=v.x; Bv[q*4+1]=v.y; Bv[q*4+2]=v.z; Bv[q*4+3]=v.w;
        }
#pragma unroll
        for (int n = 0; n < 16; ++n)
            h[n] = fmaf(__expf(Ac[n] * dt), h[n], cc * Bv[n]);
        sdt += dt;
        dptr += 2 * D_INNER; xoff += D_INNER; brow += 80;
    }
#pragma unroll
    for (int n = 0; n < 16; ++n) {
        P[(size_t)t * 16 + n] = __expf(Ac[n] * sdt);
        S[(size_t)t * 16 + n] = h[n];
    }
}

__global__ __launch_bounds__(256) void scan_combine(
    const float* __restrict__ P, const float* __restrict__ S,
    float* __restrict__ Hin, int NC)
{
    const int j = blockIdx.x * 256 + threadIdx.x;   // < NSTATE_TOT
    float h = 0.f;
    for (int c = 0; c < NC; ++c) {
        size_t idx = (size_t)c * NSTATE_TOT + j;
        Hin[idx] = h;
        h = fmaf(P[idx], h, S[idx]);
    }
}

// Re-scan from Hin; y = (h·C + xt*D)*silu(res) -> fp16 hi plane in-place over xsh.
__global__ __launch_bounds__(256) void scan_part2(
    const float* __restrict__ xr, const float* __restrict__ xdbl,
    const float* __restrict__ A_log, const float* __restrict__ Dvec,
    const float* __restrict__ Hin, short* __restrict__ xsh,
    const short* __restrict__ xsl, int CL)
{
    const int t = blockIdx.x * 256 + threadIdx.x;
    const int d = t % D_INNER;
    const int cb = t / D_INNER;
    const int b = cb % BATCH;
    const int c = cb / BATCH;
    const int l0 = c * CL;

    float Ac[16];
#pragma unroll
    for (int q = 0; q < 4; ++q) {
        float4 v = ((const float4*)(A_log + d * 16))[q];
        Ac[q*4+0] = -__expf(v.x); Ac[q*4+1] = -__expf(v.y);
        Ac[q*4+2] = -__expf(v.z); Ac[q*4+3] = -__expf(v.w);
    }
    const float Dd = Dvec[d];
    float h[16];
#pragma unroll
    for (int q = 0; q < 4; ++q) {
        float4 v = ((const float4*)(Hin + (size_t)t * 16))[q];
        h[q*4+0]=v.x; h[q*4+1]=v.y; h[q*4+2]=v.z; h[q*4+3]=v.w;
    }

    const float* dptr = xr   + ((size_t)b * SEQ + l0) * (2 * D_INNER) + d;
    const float* rptr = dptr + D_INNER;
    const float* brow = xdbl + ((size_t)b * SEQ + l0) * 80 + DT_RANK;
    size_t xoff       = ((size_t)b * SEQ + l0) * D_INNER + d;

    for (int l = 0; l < CL; ++l) {
        float dt = *dptr;
        float xt = h2f(xsh[xoff]) + h2f(xsl[xoff]);
        float res = *rptr;
        float cc = dt * xt;
        float Bv[16], Cv[16];
#pragma unroll
        for (int q = 0; q < 4; ++q) {
            float4 v = ((const float4*)brow)[q];
            Bv[q*4+0]=v.x; Bv[q*4+1]=v.y; Bv[q*4+2]=v.z; Bv[q*4+3]=v.w;
            float4 w = ((const float4*)brow)[q + 4];
            Cv[q*4+0]=w.x; Cv[q*4+1]=w.y; Cv[q*4+2]=w.z; Cv[q*4+3]=w.w;
        }
#pragma unroll
        for (int n = 0; n < 16; ++n)
            h[n] = fmaf(__expf(Ac[n] * dt), h[n], cc * Bv[n]);
        float y0 = 0.f, y1 = 0.f, y2 = 0.f, y3 = 0.f;
#pragma unroll
        for (int n = 0; n < 4; ++n) {
            y0 = fmaf(h[n],      Cv[n],      y0);
            y1 = fmaf(h[n + 4],  Cv[n + 4],  y1);
            y2 = fmaf(h[n + 8],  Cv[n + 8],  y2);
            y3 = fmaf(h[n + 12], Cv[n + 12], y3);
        }
        float y = ((y0 + y1) + (y2 + y3)) + xt * Dd;
        y *= siluf(res);
        xsh[xoff] = f2h(y);
        dptr += 2 * D_INNER; rptr += 2 * D_INNER; brow += 80; xoff += D_INNER;
    }
}

extern "C" void kernel_launch(void* const* d_in, const int* in_sizes, int n_in,
                              void* d_out, int out_size, void* d_ws, size_t ws_size,
                              hipStream_t stream) {
    const float* x      = (const float*)d_in[0];
    const float* W_in   = (const float*)d_in[1];
    const float* W_conv = (const float*)d_in[2];
    const float* b_conv = (const float*)d_in[3];
    const float* W_xproj= (const float*)d_in[4];
    const float* W_dt   = (const float*)d_in[5];
    const float* b_dt   = (const float*)d_in[6];
    const float* A_log  = (const float*)d_in[7];
    const float* Dv     = (const float*)d_in[8];
    const float* W_out  = (const float*)d_in[9];
    float* out = (float*)d_out;

    // ---- workspace layout ----
    char* base = (char*)d_ws;
    size_t off = 0;
    auto alloc = [&](size_t bytes) { char* p = base + off; off += (bytes + 255) & ~(size_t)255; return p; };

    float* xr   = (float*)alloc((size_t)BL * 3072 * 4);          // in_proj out (delta overwrites cols 0-1535)
    short* xsh  = (short*)alloc((size_t)BL * 1536 * 2);          // x-hi -> xs-hi -> y-hi plane
    short* xsl  = (short*)alloc((size_t)BL * 1536 * 2);          // xs-lo plane (scan accuracy)
    float* xdbl = (float*)alloc((size_t)BL * 80 * 4);
    short* xdh  = (short*)alloc((size_t)BL * 64 * 2);            // delta input hi plane, K padded to 64
    short* wxh  = (short*)alloc((size_t)80 * 1536 * 2);          // weight hi planes
    short* wdth = (short*)alloc((size_t)1536 * 64 * 2);
    short* woh  = (short*)alloc((size_t)768 * 1536 * 2);
    size_t fixed_end = off;
    size_t region_avail = ws_size > fixed_end ? ws_size - fixed_end : 0;

    // Time-disjoint region: {W_in plane} -> {split-K partials} -> {P/S/Hin}
    char* region = base + fixed_end;
    short* winh = (short*)region;
    float* part = (float*)region;
    int SK = (region_avail >= 8ull * BL * 80 * 4) ? 8 : 4;
    int NC = 2;
    for (int cand = 64; cand >= 2; cand >>= 1) {
        if (3ull * cand * NSTATE_TOT * 4 <= region_avail) { NC = cand; break; }
    }
    float* P    = (float*)region;
    float* S    = P + (size_t)NC * NSTATE_TOT;
    float* Hin  = S + (size_t)NC * NSTATE_TOT;
    const int CL = SEQ / NC;

    dim3 blk(256);

    // 0) operand prep: x + weights -> single fp16 planes
    cvt_all<<<dim3((GXIN + GIN + GX + GOUT + 255) / 256), blk, 0, stream>>>(
        x, W_in, W_xproj, W_out, xsh, winh, wxh, woh);
    cvt_pad_dt<<<dim3(1536 * 64 / 256), blk, 0, stream>>>(W_dt, wdth);

    // 1) in_proj: xr = x @ W_in^T   (4096x3072, K=768) — 768 blocks
    gemm_g<128, 128, 64, 64, 0><<<dim3(BL / 128, 3072 / 128, 1), blk, 0, stream>>>(
        xsh, winh, nullptr, xr, BL, 3072, 768, 768, 768, 3072, 768, 0);

    // 2) conv + SiLU -> xs hi/lo planes (overwrites x-hi; safe, in_proj done)
    conv_silu_kernel<<<dim3((BL * D_INNER) / 256), blk, 0, stream>>>(xr, W_conv, b_conv, xsh, xsl);

    // 3) x_proj split-K -> partials, then reduce -> xdbl + padded delta hi plane
    gemm_g<64, 80, 16, 80, 0><<<dim3(BL / 64, 1, SK), blk, 0, stream>>>(
        xsh, wxh, nullptr, part, BL, 80, 1536, 1536, 1536, 80, 1536 / SK, (long long)BL * 80);
    reduceK_kernel<<<dim3(BL * 80 / 256), blk, 0, stream>>>(part, xdbl, xdh, SK);

    // 4) delta = softplus(xd @ W_dt^T + b_dt) -> xr cols [0,1536)  (K padded to 64)
    gemm_g<128, 64, 64, 32, 1><<<dim3(BL / 128, 1536 / 64, 1), blk, 0, stream>>>(
        xdh, wdth, b_dt, xr, BL, 1536, 64, 64, 64, 3072, 64, 0);

    // 5) chunked scan; gated y written as fp16 hi plane in-place over xsh
    scan_part1<<<dim3(NC * BATCH * D_INNER / 256), blk, 0, stream>>>(
        xr, xsh, xsl, xdbl, A_log, P, S, CL);
    scan_combine<<<dim3(NSTATE_TOT / 256), blk, 0, stream>>>(P, S, Hin, NC);
    scan_part2<<<dim3(NC * BATCH * D_INNER / 256), blk, 0, stream>>>(
        xr, xdbl, A_log, Dv, Hin, xsh, xsl, CL);

    // 6) out_proj: out = y @ W_out^T  (4096x768, K=1536) — 384 blocks
    gemm_g<128, 64, 64, 32, 0><<<dim3(BL / 128, 768 / 64, 1), blk, 0, stream>>>(
        xsh, woh, nullptr, out, BL, 768, 1536, 1536, 1536, 768, 1536, 0);
}